// Round 1
// baseline (2674.310 us; speedup 1.0000x reference)
//
#include <hip/hip_runtime.h>
#include <math.h>

#define DEV_INLINE __device__ __forceinline__

constexpr int R_ = 256, C_ = 384, E_ = 384, H_ = 12, D_ = 32;
constexpr float NEGF = -3.402823466e38f;

// workspace layout (floats)
constexpr size_t o_qs     = 0;                                 // C*E
constexpr size_t o_p      = o_qs + (size_t)C_ * E_;            // C*H*E
constexpr size_t o_logits = o_p + (size_t)C_ * H_ * E_;        // C*H*R
constexpr size_t o_sw     = o_logits + (size_t)C_ * H_ * R_;   // C*H*R
constexpr size_t o_attn   = o_sw + (size_t)C_ * H_ * R_;       // H*C*C
constexpr size_t o_q3     = o_attn + (size_t)H_ * C_ * C_;     // H*C*R*D
constexpr size_t o_k3     = o_q3 + (size_t)H_ * C_ * R_ * D_;  // H*C*R*D
constexpr size_t o_v3     = o_q3;  // overlay: V3 written after Q3 is dead

DEV_INLINE float waveRedMax(float v) {
#pragma unroll
  for (int o = 32; o > 0; o >>= 1) v = fmaxf(v, __shfl_down(v, o));
  return v;
}
DEV_INLINE float waveRedSum(float v) {
#pragma unroll
  for (int o = 32; o > 0; o >>= 1) v += __shfl_down(v, o);
  return v;
}

// ---------------- stage 1: Qs = x[r=0] @ Wq_s * (1/sqrt(D)) ----------------
__global__ void k_qs(const float* __restrict__ x, const float* __restrict__ Wq_s,
                     float* __restrict__ ws) {
  int c = blockIdx.x, t = threadIdx.x;
  __shared__ float xl[E_];
  xl[t] = x[(size_t)c * E_ + t];  // x[0][c][t]
  __syncthreads();
  float s = 0.f;
#pragma unroll 8
  for (int k = 0; k < E_; ++k) s += xl[k] * Wq_s[(size_t)k * E_ + t];
  ws[o_qs + (size_t)c * E_ + t] = s * 0.17677669529663687f;  // 1/sqrt(32)
}

// ---------------- P[c,h,k] = sum_d Wk_s[k, h*32+d] * Qs[c, h*32+d] ----------------
__global__ void k_p(const float* __restrict__ Wk_s, float* __restrict__ ws) {
  int h = blockIdx.x, c = blockIdx.y, t = threadIdx.x;  // t = k
  __shared__ float q[D_];
  if (t < D_) q[t] = ws[o_qs + (size_t)c * E_ + h * D_ + t];
  __syncthreads();
  const float* wrow = &Wk_s[(size_t)t * E_ + h * D_];
  float s = 0.f;
#pragma unroll
  for (int d = 0; d < D_; d += 4) {
    float4 w = *(const float4*)&wrow[d];
    s += w.x * q[d] + w.y * q[d + 1] + w.z * q[d + 2] + w.w * q[d + 3];
  }
  ws[o_p + ((size_t)c * H_ + h) * E_ + t] = s;
}

// ---------------- logits[c,h,r] = sum_k x[r,c,k] * P[c,h,k] ----------------
__global__ void k_logits(const float* __restrict__ x, float* __restrict__ ws) {
  int c = blockIdx.x, t = threadIdx.x;  // t = r
  __shared__ float Pl[H_ * E_];         // 18 KiB
  for (int i = t; i < H_ * E_; i += R_) Pl[i] = ws[o_p + (size_t)c * H_ * E_ + i];
  __syncthreads();
  const float* xr = &x[((size_t)t * C_ + c) * E_];
  float acc[H_];
#pragma unroll
  for (int h = 0; h < H_; ++h) acc[h] = 0.f;
  for (int k = 0; k < E_; k += 4) {
    float4 v = *(const float4*)&xr[k];
#pragma unroll
    for (int h = 0; h < H_; ++h) {
      float4 p = *(const float4*)&Pl[h * E_ + k];
      acc[h] += v.x * p.x + v.y * p.y + v.z * p.z + v.w * p.w;
    }
  }
#pragma unroll
  for (int h = 0; h < H_; ++h)
    ws[o_logits + ((size_t)c * H_ + h) * R_ + t] = acc[h];
}

// ---------------- sw[c,h,r] = softmax_r(logits) * SCALING/sqrt(C) ----------------
__global__ void k_softmax_r(const int* __restrict__ seq_mask, float* __restrict__ ws) {
  int h = blockIdx.x, c = blockIdx.y, t = threadIdx.x;  // t = r
  int lane = t & 63, wid = t >> 6;
  float v = ws[o_logits + ((size_t)c * H_ + h) * R_ + t];
  if (seq_mask[t] == 0) v = NEGF;
  __shared__ float red[4];
  float m = waveRedMax(v);
  if (lane == 0) red[wid] = m;
  __syncthreads();
  float mx = fmaxf(fmaxf(red[0], red[1]), fmaxf(red[2], red[3]));
  __syncthreads();
  float e = expf(v - mx);
  float s = waveRedSum(e);
  if (lane == 0) red[wid] = s;
  __syncthreads();
  float sum = red[0] + red[1] + red[2] + red[3];
  const float scal = 0.17677669529663687f / sqrtf((float)C_);
  ws[o_sw + ((size_t)c * H_ + h) * R_ + t] = e / sum * scal;
}

// ---------------- Q3/K3: (x @ [Wq|Wk]), Q scaled by sw ----------------
// M = R*C (m = r*C + c), N = 768, K = 384.  64x64 tile, BK=16, 4x4/thread.
__global__ void k_qkv(const float* __restrict__ x, const float* __restrict__ Wq,
                      const float* __restrict__ Wk, float* __restrict__ ws) {
  __shared__ float As[16][68], Bs[16][68];
  int bn = blockIdx.x, bm = blockIdx.y;
  int t = threadIdx.x, tx = t & 15, ty = t >> 4;
  int m0 = bm * 64;
  bool isQ = bn < 6;
  int n0 = isQ ? bn * 64 : (bn - 6) * 64;
  const float* Bmat = isQ ? Wq : Wk;
  float acc[4][4] = {};
  int lrow = t >> 2, lkq = t & 3;
  int lkrow = t >> 4, lnq = t & 15;
  for (int k0 = 0; k0 < E_; k0 += 16) {
    float4 a4 = *(const float4*)&x[(size_t)(m0 + lrow) * E_ + k0 + lkq * 4];
    As[lkq * 4 + 0][lrow] = a4.x; As[lkq * 4 + 1][lrow] = a4.y;
    As[lkq * 4 + 2][lrow] = a4.z; As[lkq * 4 + 3][lrow] = a4.w;
    *(float4*)&Bs[lkrow][lnq * 4] =
        *(const float4*)&Bmat[(size_t)(k0 + lkrow) * E_ + n0 + lnq * 4];
    __syncthreads();
#pragma unroll
    for (int kk = 0; kk < 16; ++kk) {
      float a[4], b[4];
#pragma unroll
      for (int i = 0; i < 4; ++i) { a[i] = As[kk][ty + 16 * i]; b[i] = Bs[kk][tx + 16 * i]; }
#pragma unroll
      for (int i = 0; i < 4; ++i)
#pragma unroll
        for (int j = 0; j < 4; ++j) acc[i][j] += a[i] * b[j];
    }
    __syncthreads();
  }
#pragma unroll
  for (int i = 0; i < 4; ++i) {
    int m = m0 + ty + 16 * i;
    int r = m / C_, c = m % C_;
#pragma unroll
    for (int j = 0; j < 4; ++j) {
      int e = n0 + tx + 16 * j;
      int h = e >> 5, d = e & 31;
      size_t idx = (((size_t)h * C_ + c) * R_ + r) * D_ + d;
      if (isQ) {
        float swv = ws[o_sw + ((size_t)c * H_ + h) * R_ + r];  // includes scaling
        ws[o_q3 + idx] = acc[i][j] * swv;
      } else {
        ws[o_k3 + idx] = acc[i][j];
      }
    }
  }
}

// ---------------- QK[h,i,j] = sum_{rd} Q3[h,i,rd] * K3[h,j,rd]  (NT GEMM) ----------------
__global__ void k_qk(float* __restrict__ ws) {
  __shared__ float As[16][68], Bs[16][68];
  int bj = blockIdx.x, bi = blockIdx.y, h = blockIdx.z;
  int t = threadIdx.x, tx = t & 15, ty = t >> 4;
  const float* A = &ws[o_q3 + (size_t)h * C_ * (R_ * D_)];
  const float* Bm = &ws[o_k3 + (size_t)h * C_ * (R_ * D_)];
  float acc[4][4] = {};
  int lrow = t >> 2, lkq = t & 3;
  for (int k0 = 0; k0 < R_ * D_; k0 += 16) {
    float4 a4 = *(const float4*)&A[(size_t)(bi * 64 + lrow) * (R_ * D_) + k0 + lkq * 4];
    float4 b4 = *(const float4*)&Bm[(size_t)(bj * 64 + lrow) * (R_ * D_) + k0 + lkq * 4];
    As[lkq * 4 + 0][lrow] = a4.x; As[lkq * 4 + 1][lrow] = a4.y;
    As[lkq * 4 + 2][lrow] = a4.z; As[lkq * 4 + 3][lrow] = a4.w;
    Bs[lkq * 4 + 0][lrow] = b4.x; Bs[lkq * 4 + 1][lrow] = b4.y;
    Bs[lkq * 4 + 2][lrow] = b4.z; Bs[lkq * 4 + 3][lrow] = b4.w;
    __syncthreads();
#pragma unroll
    for (int kk = 0; kk < 16; ++kk) {
      float a[4], b[4];
#pragma unroll
      for (int i = 0; i < 4; ++i) { a[i] = As[kk][ty + 16 * i]; b[i] = Bs[kk][tx + 16 * i]; }
#pragma unroll
      for (int i = 0; i < 4; ++i)
#pragma unroll
        for (int j = 0; j < 4; ++j) acc[i][j] += a[i] * b[j];
    }
    __syncthreads();
  }
#pragma unroll
  for (int i = 0; i < 4; ++i)
#pragma unroll
    for (int j = 0; j < 4; ++j)
      ws[o_attn + ((size_t)h * C_ + bi * 64 + ty + 16 * i) * C_ + bj * 64 + tx + 16 * j] =
          acc[i][j];
}

// ---------------- softmax over j with res_mask ----------------
__global__ void k_softmax_j(const int* __restrict__ res_mask, float* __restrict__ ws) {
  int i = blockIdx.x, h = blockIdx.y, t = threadIdx.x;  // t = j
  int lane = t & 63, wid = t >> 6;  // 6 waves
  size_t base = o_attn + ((size_t)h * C_ + i) * C_;
  float v = ws[base + t];
  if ((res_mask[i] * res_mask[t]) == 0) v = NEGF;
  __shared__ float red[6];
  float m = waveRedMax(v);
  if (lane == 0) red[wid] = m;
  __syncthreads();
  float mx = red[0];
#pragma unroll
  for (int w = 1; w < 6; ++w) mx = fmaxf(mx, red[w]);
  __syncthreads();
  float e = expf(v - mx);
  float s = waveRedSum(e);
  if (lane == 0) red[wid] = s;
  __syncthreads();
  float sum = 0.f;
#pragma unroll
  for (int w = 0; w < 6; ++w) sum += red[w];
  ws[base + t] = e / sum;
}

// ---------------- V3[h,r,j,d] = (x @ Wv) ----------------
__global__ void k_v(const float* __restrict__ x, const float* __restrict__ Wv,
                    float* __restrict__ ws) {
  __shared__ float As[16][68], Bs[16][68];
  int bn = blockIdx.x, bm = blockIdx.y;
  int t = threadIdx.x, tx = t & 15, ty = t >> 4;
  int m0 = bm * 64, n0 = bn * 64;
  float acc[4][4] = {};
  int lrow = t >> 2, lkq = t & 3;
  int lkrow = t >> 4, lnq = t & 15;
  for (int k0 = 0; k0 < E_; k0 += 16) {
    float4 a4 = *(const float4*)&x[(size_t)(m0 + lrow) * E_ + k0 + lkq * 4];
    As[lkq * 4 + 0][lrow] = a4.x; As[lkq * 4 + 1][lrow] = a4.y;
    As[lkq * 4 + 2][lrow] = a4.z; As[lkq * 4 + 3][lrow] = a4.w;
    *(float4*)&Bs[lkrow][lnq * 4] =
        *(const float4*)&Wv[(size_t)(k0 + lkrow) * E_ + n0 + lnq * 4];
    __syncthreads();
#pragma unroll
    for (int kk = 0; kk < 16; ++kk) {
      float a[4], b[4];
#pragma unroll
      for (int i = 0; i < 4; ++i) { a[i] = As[kk][ty + 16 * i]; b[i] = Bs[kk][tx + 16 * i]; }
#pragma unroll
      for (int i = 0; i < 4; ++i)
#pragma unroll
        for (int j = 0; j < 4; ++j) acc[i][j] += a[i] * b[j];
    }
    __syncthreads();
  }
#pragma unroll
  for (int i = 0; i < 4; ++i) {
    int m = m0 + ty + 16 * i;
    int r = m / C_, c = m % C_;  // c = j index
#pragma unroll
    for (int j = 0; j < 4; ++j) {
      int e = n0 + tx + 16 * j;
      int h = e >> 5, d = e & 31;
      ws[o_v3 + (((size_t)h * R_ + r) * C_ + c) * D_ + d] = acc[i][j];
    }
  }
}

// ---------------- out[r,i,h,d] = sum_j attn[h,i,j] * V3[h,r,j,d] ----------------
__global__ void k_out(const float* __restrict__ ws_c, float* __restrict__ out) {
  __shared__ float At[64][68];
  __shared__ float Vs[64][32];
  int bi = blockIdx.x, r = blockIdx.y, h = blockIdx.z;
  int t = threadIdx.x;
  int dg = t & 7, iq = t >> 3;  // dg: float4 group of d, iq: 0..31
  float4 acc0 = {0, 0, 0, 0}, acc1 = {0, 0, 0, 0};
  const float* attn = &ws_c[o_attn + (size_t)h * C_ * C_];
  const float* V = &ws_c[o_v3 + ((size_t)h * R_ + r) * C_ * D_];
  for (int j0 = 0; j0 < C_; j0 += 64) {
    int row = t >> 4, jq = t & 15;
#pragma unroll
    for (int p = 0; p < 4; ++p)
      *(float4*)&At[row + 16 * p][jq * 4] =
          *(const float4*)&attn[(size_t)(bi * 64 + row + 16 * p) * C_ + j0 + jq * 4];
    int jr = t >> 3, dq = t & 7;
#pragma unroll
    for (int p = 0; p < 2; ++p)
      *(float4*)&Vs[jr + 32 * p][dq * 4] =
          *(const float4*)&V[(size_t)(j0 + jr + 32 * p) * D_ + dq * 4];
    __syncthreads();
#pragma unroll 16
    for (int j = 0; j < 64; ++j) {
      float4 v = *(const float4*)&Vs[j][dg * 4];
      float a0 = At[iq][j], a1 = At[iq + 32][j];
      acc0.x += a0 * v.x; acc0.y += a0 * v.y; acc0.z += a0 * v.z; acc0.w += a0 * v.w;
      acc1.x += a1 * v.x; acc1.y += a1 * v.y; acc1.z += a1 * v.z; acc1.w += a1 * v.w;
    }
    __syncthreads();
  }
  int i0 = bi * 64 + iq;
  *(float4*)&out[(((size_t)r * C_ + i0) * H_ + h) * D_ + dg * 4] = acc0;
  *(float4*)&out[(((size_t)r * C_ + i0 + 32) * H_ + h) * D_ + dg * 4] = acc1;
}

extern "C" void kernel_launch(void* const* d_in, const int* in_sizes, int n_in,
                              void* d_out, int out_size, void* d_ws, size_t ws_size,
                              hipStream_t stream) {
  const float* x = (const float*)d_in[0];
  const float* Wq = (const float*)d_in[1];
  const float* Wk = (const float*)d_in[2];
  const float* Wv = (const float*)d_in[3];
  const float* Wq_s = (const float*)d_in[4];
  const float* Wk_s = (const float*)d_in[5];
  const int* res_mask = (const int*)d_in[6];
  const int* seq_mask = (const int*)d_in[7];
  float* ws = (float*)d_ws;
  float* out = (float*)d_out;

  hipLaunchKernelGGL(k_qs, dim3(C_), dim3(E_), 0, stream, x, Wq_s, ws);
  hipLaunchKernelGGL(k_p, dim3(H_, C_), dim3(E_), 0, stream, Wk_s, ws);
  hipLaunchKernelGGL(k_logits, dim3(C_), dim3(R_), 0, stream, x, ws);
  hipLaunchKernelGGL(k_softmax_r, dim3(H_, C_), dim3(R_), 0, stream, seq_mask, ws);
  hipLaunchKernelGGL(k_qkv, dim3(12, 1536), dim3(256), 0, stream, x, Wq, Wk, ws);
  hipLaunchKernelGGL(k_qk, dim3(6, 6, 12), dim3(256), 0, stream, ws);
  hipLaunchKernelGGL(k_softmax_j, dim3(C_, H_), dim3(C_), 0, stream, res_mask, ws);
  hipLaunchKernelGGL(k_v, dim3(6, 1536), dim3(256), 0, stream, x, Wv, ws);
  hipLaunchKernelGGL(k_out, dim3(6, R_, H_), dim3(256), 0, stream, ws, out);
}

// Round 5
// 2092.681 us; speedup vs baseline: 1.2779x; 1.2779x over previous
//
#include <hip/hip_runtime.h>
#include <math.h>

#define DEV_INLINE __device__ __forceinline__

constexpr int R_ = 256, C_ = 384, E_ = 384, H_ = 12, D_ = 32;
constexpr float NEGF = -3.402823466e38f;

typedef __attribute__((ext_vector_type(4))) float f32x4;
typedef __attribute__((ext_vector_type(8))) short short8;
typedef __attribute__((ext_vector_type(4))) unsigned short u16x4;

// ---------------- workspace layout (R1's float offsets, proven) ----------------
constexpr size_t o_qs     = 0;                                 // C*E
constexpr size_t o_p      = o_qs + (size_t)C_ * E_;            // C*H*E
constexpr size_t o_logits = o_p + (size_t)C_ * H_ * E_;        // C*H*R
constexpr size_t o_sw     = o_logits + (size_t)C_ * H_ * R_;   // C*H*R
constexpr size_t o_attn   = o_sw + (size_t)C_ * H_ * R_;       // H*C*C
constexpr size_t o_q3     = o_attn + (size_t)H_ * C_ * C_;     // H*C*R*D f32
constexpr size_t o_k3     = o_q3 + (size_t)H_ * C_ * R_ * D_;  // H*C*R*D f32
// byte overlays (on dead regions):
constexpr size_t ob_wvh = 0;                      // 384*384 bf16 = 294,912 B (over o_qs, dead after k_p)
constexpr size_t ob_wvl = ob_wvh + 294912;        // ends 589,824 = o_p*4 exactly
constexpr size_t ob_v3h = o_q3 * 4;               // 12*8192*384 bf16 = 75,497,472 B (over Q3f, dead after k_qk)
constexpr size_t ob_v3l = ob_v3h + 75497472;      // ends 175,177,728 = o_k3*4 exactly

// ---------------- helpers ----------------
DEV_INLINE unsigned short bf16h(float x) {
  unsigned int u = __builtin_bit_cast(unsigned int, x);
  unsigned int r = (u + 0x7FFFu + ((u >> 16) & 1u)) >> 16;
  return (unsigned short)r;
}
DEV_INLINE void split2(float x, unsigned short& h, unsigned short& l) {
  h = bf16h(x);
  float hf = __builtin_bit_cast(float, ((unsigned int)h) << 16);
  l = bf16h(x - hf);
}
DEV_INLINE float waveRedMax(float v) {
#pragma unroll
  for (int o = 32; o > 0; o >>= 1) v = fmaxf(v, __shfl_down(v, o));
  return v;
}
DEV_INLINE float waveRedSum(float v) {
#pragma unroll
  for (int o = 32; o > 0; o >>= 1) v += __shfl_down(v, o);
  return v;
}

// ---------------- MFMA tile machinery (padded linear LDS) ----------------
constexpr int LROW = 40;
constexpr int LDS_TILE = 128 * LROW;

DEV_INLINE void stage_f32(const float* __restrict__ src, int lda,
                          unsigned short* dH, unsigned short* dL) {
  int t = threadIdx.x;
  int row = t >> 1, half = t & 1;
  const float* p = src + (size_t)row * lda + half * 16;
  unsigned short h[16], l[16];
#pragma unroll
  for (int i = 0; i < 4; ++i) {
    float4 f = *(const float4*)(p + i * 4);
    split2(f.x, h[i * 4 + 0], l[i * 4 + 0]);
    split2(f.y, h[i * 4 + 1], l[i * 4 + 1]);
    split2(f.z, h[i * 4 + 2], l[i * 4 + 2]);
    split2(f.w, h[i * 4 + 3], l[i * 4 + 3]);
  }
  unsigned short* db = dH + row * LROW + half * 16;
  unsigned short* dbl = dL + row * LROW + half * 16;
  *(short8*)(db + 0) = *(const short8*)&h[0];
  *(short8*)(db + 8) = *(const short8*)&h[8];
  *(short8*)(dbl + 0) = *(const short8*)&l[0];
  *(short8*)(dbl + 8) = *(const short8*)&l[8];
}

DEV_INLINE void stage_bf16(const unsigned short* __restrict__ src, int lda,
                           unsigned short* d) {
  int t = threadIdx.x;
  int row = t >> 1, half = t & 1;
  const unsigned short* p = src + (size_t)row * lda + half * 16;
  short8 v0 = *(const short8*)(p);
  short8 v1 = *(const short8*)(p + 8);
  unsigned short* db = d + row * LROW + half * 16;
  *(short8*)(db + 0) = v0;
  *(short8*)(db + 8) = v1;
}

DEV_INLINE void chunk_mma(const unsigned short* aH, const unsigned short* aL,
                          const unsigned short* bH, const unsigned short* bL,
                          int wr, int wc, f32x4 acc[4][4]) {
  int lane = threadIdx.x & 63;
  int id16 = lane & 15, g = lane >> 4;
  short8 Ah[4], Al[4], Bh[4], Bl[4];
#pragma unroll
  for (int mi = 0; mi < 4; ++mi) {
    int row = wr * 64 + mi * 16 + id16;
    int addr = row * LROW + (g << 3);
    Ah[mi] = *(const short8*)(aH + addr);
    Al[mi] = *(const short8*)(aL + addr);
  }
#pragma unroll
  for (int ni = 0; ni < 4; ++ni) {
    int col = wc * 64 + ni * 16 + id16;
    int addr = col * LROW + (g << 3);
    Bh[ni] = *(const short8*)(bH + addr);
    Bl[ni] = *(const short8*)(bL + addr);
  }
#pragma unroll
  for (int mi = 0; mi < 4; ++mi)
#pragma unroll
    for (int ni = 0; ni < 4; ++ni) {
      acc[mi][ni] = __builtin_amdgcn_mfma_f32_16x16x32_bf16(Ah[mi], Bh[ni], acc[mi][ni], 0, 0, 0);
      acc[mi][ni] = __builtin_amdgcn_mfma_f32_16x16x32_bf16(Ah[mi], Bl[ni], acc[mi][ni], 0, 0, 0);
      acc[mi][ni] = __builtin_amdgcn_mfma_f32_16x16x32_bf16(Al[mi], Bh[ni], acc[mi][ni], 0, 0, 0);
      acc[mi][ni] = __builtin_amdgcn_mfma_f32_16x16x32_bf16(Al[mi], Bl[ni], acc[mi][ni], 0, 0, 0);
    }
}

#define MMA_PROLOGUE                                        \
  __shared__ unsigned short aH[LDS_TILE], aL[LDS_TILE];     \
  __shared__ unsigned short bH[LDS_TILE], bL[LDS_TILE];     \
  int wave = threadIdx.x >> 6, wr = wave >> 1, wc = wave & 1; \
  f32x4 acc[4][4];                                          \
  _Pragma("unroll") for (int mi = 0; mi < 4; ++mi)          \
  _Pragma("unroll") for (int ni = 0; ni < 4; ++ni)          \
      acc[mi][ni] = (f32x4){0.f, 0.f, 0.f, 0.f};

// ================= R1-VERBATIM STAGE 1 =================
__global__ void k_qs(const float* __restrict__ x, const float* __restrict__ Wq_s,
                     float* __restrict__ ws) {
  int c = blockIdx.x, t = threadIdx.x;
  __shared__ float xl[E_];
  xl[t] = x[(size_t)c * E_ + t];
  __syncthreads();
  float s = 0.f;
#pragma unroll 8
  for (int k = 0; k < E_; ++k) s += xl[k] * Wq_s[(size_t)k * E_ + t];
  ws[o_qs + (size_t)c * E_ + t] = s * 0.17677669529663687f;
}

__global__ void k_p(const float* __restrict__ Wk_s, float* __restrict__ ws) {
  int h = blockIdx.x, c = blockIdx.y, t = threadIdx.x;
  __shared__ float q[D_];
  if (t < D_) q[t] = ws[o_qs + (size_t)c * E_ + h * D_ + t];
  __syncthreads();
  const float* wrow = &Wk_s[(size_t)t * E_ + h * D_];
  float s = 0.f;
#pragma unroll
  for (int d = 0; d < D_; d += 4) {
    float4 w = *(const float4*)&wrow[d];
    s += w.x * q[d] + w.y * q[d + 1] + w.z * q[d + 2] + w.w * q[d + 3];
  }
  ws[o_p + ((size_t)c * H_ + h) * E_ + t] = s;
}

__global__ void k_logits(const float* __restrict__ x, float* __restrict__ ws) {
  int c = blockIdx.x, t = threadIdx.x;
  __shared__ float Pl[H_ * E_];
  for (int i = t; i < H_ * E_; i += R_) Pl[i] = ws[o_p + (size_t)c * H_ * E_ + i];
  __syncthreads();
  const float* xr = &x[((size_t)t * C_ + c) * E_];
  float acc[H_];
#pragma unroll
  for (int h = 0; h < H_; ++h) acc[h] = 0.f;
  for (int k = 0; k < E_; k += 4) {
    float4 v = *(const float4*)&xr[k];
#pragma unroll
    for (int h = 0; h < H_; ++h) {
      float4 p = *(const float4*)&Pl[h * E_ + k];
      acc[h] += v.x * p.x + v.y * p.y + v.z * p.z + v.w * p.w;
    }
  }
#pragma unroll
  for (int h = 0; h < H_; ++h)
    ws[o_logits + ((size_t)c * H_ + h) * R_ + t] = acc[h];
}

__global__ void k_softmax_r(const int* __restrict__ seq_mask, float* __restrict__ ws) {
  int h = blockIdx.x, c = blockIdx.y, t = threadIdx.x;
  int lane = t & 63, wid = t >> 6;
  float v = ws[o_logits + ((size_t)c * H_ + h) * R_ + t];
  if (seq_mask[t] == 0) v = NEGF;
  __shared__ float red[4];
  float m = waveRedMax(v);
  if (lane == 0) red[wid] = m;
  __syncthreads();
  float mx = fmaxf(fmaxf(red[0], red[1]), fmaxf(red[2], red[3]));
  __syncthreads();
  float e = expf(v - mx);
  float s = waveRedSum(e);
  if (lane == 0) red[wid] = s;
  __syncthreads();
  float sum = red[0] + red[1] + red[2] + red[3];
  const float scal = 0.17677669529663687f / sqrtf((float)C_);
  ws[o_sw + ((size_t)c * H_ + h) * R_ + t] = e / sum * scal;
}

// ================= R1-VERBATIM fp32 Q/K PROJ + QK + SOFTMAX =================
__global__ void k_qkv(const float* __restrict__ x, const float* __restrict__ Wq,
                      const float* __restrict__ Wk, float* __restrict__ ws) {
  __shared__ float As[16][68], Bs[16][68];
  int bn = blockIdx.x, bm = blockIdx.y;
  int t = threadIdx.x, tx = t & 15, ty = t >> 4;
  int m0 = bm * 64;
  bool isQ = bn < 6;
  int n0 = isQ ? bn * 64 : (bn - 6) * 64;
  const float* Bmat = isQ ? Wq : Wk;
  float acc[4][4] = {};
  int lrow = t >> 2, lkq = t & 3;
  int lkrow = t >> 4, lnq = t & 15;
  for (int k0 = 0; k0 < E_; k0 += 16) {
    float4 a4 = *(const float4*)&x[(size_t)(m0 + lrow) * E_ + k0 + lkq * 4];
    As[lkq * 4 + 0][lrow] = a4.x; As[lkq * 4 + 1][lrow] = a4.y;
    As[lkq * 4 + 2][lrow] = a4.z; As[lkq * 4 + 3][lrow] = a4.w;
    *(float4*)&Bs[lkrow][lnq * 4] =
        *(const float4*)&Bmat[(size_t)(k0 + lkrow) * E_ + n0 + lnq * 4];
    __syncthreads();
#pragma unroll
    for (int kk = 0; kk < 16; ++kk) {
      float a[4], b[4];
#pragma unroll
      for (int i = 0; i < 4; ++i) { a[i] = As[kk][ty + 16 * i]; b[i] = Bs[kk][tx + 16 * i]; }
#pragma unroll
      for (int i = 0; i < 4; ++i)
#pragma unroll
        for (int j = 0; j < 4; ++j) acc[i][j] += a[i] * b[j];
    }
    __syncthreads();
  }
#pragma unroll
  for (int i = 0; i < 4; ++i) {
    int m = m0 + ty + 16 * i;
    int r = m / C_, c = m % C_;
#pragma unroll
    for (int j = 0; j < 4; ++j) {
      int e = n0 + tx + 16 * j;
      int h = e >> 5, d = e & 31;
      size_t idx = (((size_t)h * C_ + c) * R_ + r) * D_ + d;
      if (isQ) {
        float swv = ws[o_sw + ((size_t)c * H_ + h) * R_ + r];
        ws[o_q3 + idx] = acc[i][j] * swv;
      } else {
        ws[o_k3 + idx] = acc[i][j];
      }
    }
  }
}

__global__ void k_qk(float* __restrict__ ws) {
  __shared__ float As[16][68], Bs[16][68];
  int bj = blockIdx.x, bi = blockIdx.y, h = blockIdx.z;
  int t = threadIdx.x, tx = t & 15, ty = t >> 4;
  const float* A = &ws[o_q3 + (size_t)h * C_ * (R_ * D_)];
  const float* Bm = &ws[o_k3 + (size_t)h * C_ * (R_ * D_)];
  float acc[4][4] = {};
  int lrow = t >> 2, lkq = t & 3;
  for (int k0 = 0; k0 < R_ * D_; k0 += 16) {
    float4 a4 = *(const float4*)&A[(size_t)(bi * 64 + lrow) * (R_ * D_) + k0 + lkq * 4];
    float4 b4 = *(const float4*)&Bm[(size_t)(bj * 64 + lrow) * (R_ * D_) + k0 + lkq * 4];
    As[lkq * 4 + 0][lrow] = a4.x; As[lkq * 4 + 1][lrow] = a4.y;
    As[lkq * 4 + 2][lrow] = a4.z; As[lkq * 4 + 3][lrow] = a4.w;
    Bs[lkq * 4 + 0][lrow] = b4.x; Bs[lkq * 4 + 1][lrow] = b4.y;
    Bs[lkq * 4 + 2][lrow] = b4.z; Bs[lkq * 4 + 3][lrow] = b4.w;
    __syncthreads();
#pragma unroll
    for (int kk = 0; kk < 16; ++kk) {
      float a[4], b[4];
#pragma unroll
      for (int i = 0; i < 4; ++i) { a[i] = As[kk][ty + 16 * i]; b[i] = Bs[kk][tx + 16 * i]; }
#pragma unroll
      for (int i = 0; i < 4; ++i)
#pragma unroll
        for (int j = 0; j < 4; ++j) acc[i][j] += a[i] * b[j];
    }
    __syncthreads();
  }
#pragma unroll
  for (int i = 0; i < 4; ++i)
#pragma unroll
    for (int j = 0; j < 4; ++j)
      ws[o_attn + ((size_t)h * C_ + bi * 64 + ty + 16 * i) * C_ + bj * 64 + tx + 16 * j] =
          acc[i][j];
}

__global__ void k_softmax_j(const int* __restrict__ res_mask, float* __restrict__ ws) {
  int i = blockIdx.x, h = blockIdx.y, t = threadIdx.x;
  int lane = t & 63, wid = t >> 6;
  size_t base = o_attn + ((size_t)h * C_ + i) * C_;
  float v = ws[base + t];
  if ((res_mask[i] * res_mask[t]) == 0) v = NEGF;
  __shared__ float red[6];
  float m = waveRedMax(v);
  if (lane == 0) red[wid] = m;
  __syncthreads();
  float mx = red[0];
#pragma unroll
  for (int w = 1; w < 6; ++w) mx = fmaxf(mx, red[w]);
  __syncthreads();
  float e = expf(v - mx);
  float s = waveRedSum(e);
  if (lane == 0) red[wid] = s;
  __syncthreads();
  float sum = 0.f;
#pragma unroll
  for (int w = 0; w < 6; ++w) sum += red[w];
  ws[base + t] = e / sum;
}

// ================= NEW: MFMA V-projection + PV =================
__global__ void k_cvt_wv(const float* __restrict__ Wv, unsigned short* __restrict__ Wvh,
                         unsigned short* __restrict__ Wvl) {
  int n = blockIdx.x, k = threadIdx.x;
  float w = Wv[(size_t)k * 384 + n];
  unsigned short h, l;
  split2(w, h, l);
  Wvh[(size_t)n * 384 + k] = h;
  Wvl[(size_t)n * 384 + k] = l;
}

// V3[h][r*32+d][c] = x @ Wv  (hi/lo bf16), MFMA
__global__ __launch_bounds__(256) void k_v_mma(
    const float* __restrict__ x, const unsigned short* __restrict__ Wvh,
    const unsigned short* __restrict__ Wvl, unsigned short* __restrict__ V3h,
    unsigned short* __restrict__ V3l) {
  MMA_PROLOGUE
  int n0 = blockIdx.x * 128, m0 = blockIdx.y * 128;
  for (int k0 = 0; k0 < 384; k0 += 32) {
    stage_f32(x + (size_t)m0 * 384 + k0, 384, aH, aL);
    stage_bf16(Wvh + (size_t)n0 * 384 + k0, 384, bH);
    stage_bf16(Wvl + (size_t)n0 * 384 + k0, 384, bL);
    __syncthreads();
    chunk_mma(aH, aL, bH, bL, wr, wc, acc);
    __syncthreads();
  }
  int lane = threadIdx.x & 63, id16 = lane & 15, l4 = (lane >> 4) * 4;
#pragma unroll
  for (int mi = 0; mi < 4; ++mi) {
#pragma unroll
    for (int ni = 0; ni < 4; ++ni) {
      int n = n0 + wc * 64 + ni * 16 + id16;  // 0..383 -> (h,d)
      int hh = n >> 5, dd = n & 31;
      int mbase = m0 + wr * 64 + mi * 16 + l4;
      int r = mbase / 384, c0 = mbase - r * 384;  // 4 regs = 4 consecutive c
      f32x4 a = acc[mi][ni];
      u16x4 hv, lv;
#pragma unroll
      for (int reg = 0; reg < 4; ++reg) {
        unsigned short hb, lb;
        split2(a[reg], hb, lb);
        hv[reg] = hb;
        lv[reg] = lb;
      }
      size_t off = ((size_t)hh * 8192 + r * 32 + dd) * 384 + c0;
      *(u16x4*)(V3h + off) = hv;
      *(u16x4*)(V3l + off) = lv;
    }
  }
}

// out[r,i,h,d] = sum_j attn[h,i,j] * V3[h][r*32+d][j]  (attn fp32 -> split on stage)
__global__ __launch_bounds__(256) void k_out_mma(
    const float* __restrict__ ws_c, const unsigned short* __restrict__ V3h,
    const unsigned short* __restrict__ V3l, float* __restrict__ out) {
  MMA_PROLOGUE
  int n0 = blockIdx.x * 128, m0 = blockIdx.y * 128, h = blockIdx.z;
  const float* att = ws_c + o_attn + (size_t)h * 384 * 384;
  const unsigned short* Bb = V3h + (size_t)h * 8192 * 384;
  const unsigned short* Bl_ = V3l + (size_t)h * 8192 * 384;
  for (int k0 = 0; k0 < 384; k0 += 32) {
    stage_f32(att + (size_t)m0 * 384 + k0, 384, aH, aL);
    stage_bf16(Bb + (size_t)n0 * 384 + k0, 384, bH);
    stage_bf16(Bl_ + (size_t)n0 * 384 + k0, 384, bL);
    __syncthreads();
    chunk_mma(aH, aL, bH, bL, wr, wc, acc);
    __syncthreads();
  }
  int lane = threadIdx.x & 63, id16 = lane & 15, l4 = (lane >> 4) * 4;
#pragma unroll
  for (int mi = 0; mi < 4; ++mi)
#pragma unroll
    for (int ni = 0; ni < 4; ++ni) {
      int i0 = m0 + wr * 64 + mi * 16 + l4;
      int n = n0 + wc * 64 + ni * 16 + id16;  // rd index
      int r = n >> 5, d = n & 31;
      f32x4 a = acc[mi][ni];
#pragma unroll
      for (int reg = 0; reg < 4; ++reg)
        out[(((size_t)r * 384 + i0 + reg) * 12 + h) * 32 + d] = a[reg];
    }
}

extern "C" void kernel_launch(void* const* d_in, const int* in_sizes, int n_in,
                              void* d_out, int out_size, void* d_ws, size_t ws_size,
                              hipStream_t stream) {
  const float* x = (const float*)d_in[0];
  const float* Wq = (const float*)d_in[1];
  const float* Wk = (const float*)d_in[2];
  const float* Wv = (const float*)d_in[3];
  const float* Wq_s = (const float*)d_in[4];
  const float* Wk_s = (const float*)d_in[5];
  const int* res_mask = (const int*)d_in[6];
  const int* seq_mask = (const int*)d_in[7];
  float* ws = (float*)d_ws;
  char* wsb = (char*)d_ws;
  float* out = (float*)d_out;

  unsigned short* Wvh = (unsigned short*)(wsb + ob_wvh);
  unsigned short* Wvl = (unsigned short*)(wsb + ob_wvl);
  unsigned short* V3h = (unsigned short*)(wsb + ob_v3h);
  unsigned short* V3l = (unsigned short*)(wsb + ob_v3l);

  hipLaunchKernelGGL(k_qs, dim3(C_), dim3(E_), 0, stream, x, Wq_s, ws);
  hipLaunchKernelGGL(k_p, dim3(H_, C_), dim3(E_), 0, stream, Wk_s, ws);
  hipLaunchKernelGGL(k_logits, dim3(C_), dim3(R_), 0, stream, x, ws);
  hipLaunchKernelGGL(k_softmax_r, dim3(H_, C_), dim3(R_), 0, stream, seq_mask, ws);
  // Wv hi/lo overlays o_qs (dead after k_p)
  hipLaunchKernelGGL(k_cvt_wv, dim3(384), dim3(384), 0, stream, Wv, Wvh, Wvl);
  hipLaunchKernelGGL(k_qkv, dim3(12, 1536), dim3(256), 0, stream, x, Wq, Wk, ws);
  hipLaunchKernelGGL(k_qk, dim3(6, 6, 12), dim3(256), 0, stream, ws);
  hipLaunchKernelGGL(k_softmax_j, dim3(C_, H_), dim3(C_), 0, stream, res_mask, ws);
  // V3 hi/lo overlays Q3f (dead after k_qk)
  hipLaunchKernelGGL(k_v_mma, dim3(3, 768), dim3(256), 0, stream, x, Wvh, Wvl, V3h, V3l);
  hipLaunchKernelGGL(k_out_mma, dim3(64, 3, 12), dim3(256), 0, stream, ws, V3h, V3l, out);
}

// Round 9
// 864.340 us; speedup vs baseline: 3.0940x; 2.4211x over previous
//
#include <hip/hip_runtime.h>
#include <math.h>

#define DEV_INLINE __device__ __forceinline__

constexpr int R_ = 256, C_ = 384, E_ = 384, H_ = 12, D_ = 32;
constexpr float NEGF = -3.402823466e38f;

typedef __attribute__((ext_vector_type(4))) float f32x4;
typedef __attribute__((ext_vector_type(8))) short short8;
typedef __attribute__((ext_vector_type(4))) unsigned short u16x4;

// ---------------- workspace layout (R1 float offsets, proven) ----------------
constexpr size_t o_qs     = 0;                                 // C*E
constexpr size_t o_p      = o_qs + (size_t)C_ * E_;            // C*H*E
constexpr size_t o_logits = o_p + (size_t)C_ * H_ * E_;        // C*H*R
constexpr size_t o_sw     = o_logits + (size_t)C_ * H_ * R_;   // C*H*R
constexpr size_t o_attn   = o_sw + (size_t)C_ * H_ * R_;       // H*C*C (QKf -> attn in place)
constexpr size_t o_q3     = o_attn + (size_t)H_ * C_ * C_;     // big region start
// byte overlays on dead regions:
constexpr size_t ob_wvh = 0;                       // over o_qs (dead after k_p)
constexpr size_t ob_wvl = ob_wvh + 294912;
constexpr size_t ob_wtb = o_logits * 4;            // over o_logits (dead after softmax_r)
constexpr size_t ob_q3b = o_q3 * 4;                // 12*384*8192 bf16 = 75,497,472 B
constexpr size_t ob_k3b = ob_q3b + 75497472;       // ends 175,177,728
constexpr size_t ob_v3h = ob_q3b;                  // V3 overlays Q3b/K3b (dead after k_qk_mma)
constexpr size_t ob_v3l = ob_v3h + 75497472;

// ---------------- helpers ----------------
DEV_INLINE unsigned short bf16h(float x) {
  unsigned int u = __builtin_bit_cast(unsigned int, x);
  unsigned int r = (u + 0x7FFFu + ((u >> 16) & 1u)) >> 16;
  return (unsigned short)r;
}
DEV_INLINE void split2(float x, unsigned short& h, unsigned short& l) {
  h = bf16h(x);
  float hf = __builtin_bit_cast(float, ((unsigned int)h) << 16);
  l = bf16h(x - hf);
}
DEV_INLINE float waveRedMax(float v) {
#pragma unroll
  for (int o = 32; o > 0; o >>= 1) v = fmaxf(v, __shfl_down(v, o));
  return v;
}
DEV_INLINE float waveRedSum(float v) {
#pragma unroll
  for (int o = 32; o > 0; o >>= 1) v += __shfl_down(v, o);
  return v;
}

// ---------------- MFMA tile machinery (padded linear LDS; verified R5) ----------------
constexpr int LROW = 40;
constexpr int LDS_TILE = 128 * LROW;

DEV_INLINE void stage_f32(const float* __restrict__ src, int lda,
                          unsigned short* dH, unsigned short* dL) {
  int t = threadIdx.x;
  int row = t >> 1, half = t & 1;
  const float* p = src + (size_t)row * lda + half * 16;
  unsigned short h[16], l[16];
#pragma unroll
  for (int i = 0; i < 4; ++i) {
    float4 f = *(const float4*)(p + i * 4);
    split2(f.x, h[i * 4 + 0], l[i * 4 + 0]);
    split2(f.y, h[i * 4 + 1], l[i * 4 + 1]);
    split2(f.z, h[i * 4 + 2], l[i * 4 + 2]);
    split2(f.w, h[i * 4 + 3], l[i * 4 + 3]);
  }
  unsigned short* db = dH + row * LROW + half * 16;
  unsigned short* dbl = dL + row * LROW + half * 16;
  *(short8*)(db + 0) = *(const short8*)&h[0];
  *(short8*)(db + 8) = *(const short8*)&h[8];
  *(short8*)(dbl + 0) = *(const short8*)&l[0];
  *(short8*)(dbl + 8) = *(const short8*)&l[8];
}

DEV_INLINE void stage_f32h(const float* __restrict__ src, int lda, unsigned short* dH) {
  int t = threadIdx.x;
  int row = t >> 1, half = t & 1;
  const float* p = src + (size_t)row * lda + half * 16;
  unsigned short h[16];
#pragma unroll
  for (int i = 0; i < 4; ++i) {
    float4 f = *(const float4*)(p + i * 4);
    h[i * 4 + 0] = bf16h(f.x);
    h[i * 4 + 1] = bf16h(f.y);
    h[i * 4 + 2] = bf16h(f.z);
    h[i * 4 + 3] = bf16h(f.w);
  }
  unsigned short* db = dH + row * LROW + half * 16;
  *(short8*)(db + 0) = *(const short8*)&h[0];
  *(short8*)(db + 8) = *(const short8*)&h[8];
}

DEV_INLINE void stage_bf16(const unsigned short* __restrict__ src, int lda,
                           unsigned short* d) {
  int t = threadIdx.x;
  int row = t >> 1, half = t & 1;
  const unsigned short* p = src + (size_t)row * lda + half * 16;
  short8 v0 = *(const short8*)(p);
  short8 v1 = *(const short8*)(p + 8);
  unsigned short* db = d + row * LROW + half * 16;
  *(short8*)(db + 0) = v0;
  *(short8*)(db + 8) = v1;
}

DEV_INLINE void chunk_mma(const unsigned short* aH, const unsigned short* aL,
                          const unsigned short* bH, const unsigned short* bL,
                          int wr, int wc, f32x4 acc[4][4]) {
  int lane = threadIdx.x & 63;
  int id16 = lane & 15, g = lane >> 4;
  short8 Ah[4], Al[4], Bh[4], Bl[4];
#pragma unroll
  for (int mi = 0; mi < 4; ++mi) {
    int row = wr * 64 + mi * 16 + id16;
    int addr = row * LROW + (g << 3);
    Ah[mi] = *(const short8*)(aH + addr);
    Al[mi] = *(const short8*)(aL + addr);
  }
#pragma unroll
  for (int ni = 0; ni < 4; ++ni) {
    int col = wc * 64 + ni * 16 + id16;
    int addr = col * LROW + (g << 3);
    Bh[ni] = *(const short8*)(bH + addr);
    Bl[ni] = *(const short8*)(bL + addr);
  }
#pragma unroll
  for (int mi = 0; mi < 4; ++mi)
#pragma unroll
    for (int ni = 0; ni < 4; ++ni) {
      acc[mi][ni] = __builtin_amdgcn_mfma_f32_16x16x32_bf16(Ah[mi], Bh[ni], acc[mi][ni], 0, 0, 0);
      acc[mi][ni] = __builtin_amdgcn_mfma_f32_16x16x32_bf16(Ah[mi], Bl[ni], acc[mi][ni], 0, 0, 0);
      acc[mi][ni] = __builtin_amdgcn_mfma_f32_16x16x32_bf16(Al[mi], Bh[ni], acc[mi][ni], 0, 0, 0);
      acc[mi][ni] = __builtin_amdgcn_mfma_f32_16x16x32_bf16(Al[mi], Bl[ni], acc[mi][ni], 0, 0, 0);
    }
}

DEV_INLINE void chunk_mma1(const unsigned short* aB, const unsigned short* bB,
                           int wr, int wc, f32x4 acc[4][4]) {
  int lane = threadIdx.x & 63;
  int id16 = lane & 15, g = lane >> 4;
  short8 A[4], B[4];
#pragma unroll
  for (int mi = 0; mi < 4; ++mi) {
    int row = wr * 64 + mi * 16 + id16;
    A[mi] = *(const short8*)(aB + row * LROW + (g << 3));
  }
#pragma unroll
  for (int ni = 0; ni < 4; ++ni) {
    int col = wc * 64 + ni * 16 + id16;
    B[ni] = *(const short8*)(bB + col * LROW + (g << 3));
  }
#pragma unroll
  for (int mi = 0; mi < 4; ++mi)
#pragma unroll
    for (int ni = 0; ni < 4; ++ni)
      acc[mi][ni] = __builtin_amdgcn_mfma_f32_16x16x32_bf16(A[mi], B[ni], acc[mi][ni], 0, 0, 0);
}

#define MMA_PROLOGUE                                        \
  __shared__ unsigned short aH[LDS_TILE], aL[LDS_TILE];     \
  __shared__ unsigned short bH[LDS_TILE], bL[LDS_TILE];     \
  int wave = threadIdx.x >> 6, wr = wave >> 1, wc = wave & 1; \
  f32x4 acc[4][4];                                          \
  _Pragma("unroll") for (int mi = 0; mi < 4; ++mi)          \
  _Pragma("unroll") for (int ni = 0; ni < 4; ++ni)          \
      acc[mi][ni] = (f32x4){0.f, 0.f, 0.f, 0.f};

#define MMA_PROLOGUE1                                       \
  __shared__ unsigned short aB[LDS_TILE], bB[LDS_TILE];     \
  int wave = threadIdx.x >> 6, wr = wave >> 1, wc = wave & 1; \
  f32x4 acc[4][4];                                          \
  _Pragma("unroll") for (int mi = 0; mi < 4; ++mi)          \
  _Pragma("unroll") for (int ni = 0; ni < 4; ++ni)          \
      acc[mi][ni] = (f32x4){0.f, 0.f, 0.f, 0.f};

// ================= R1-VERBATIM STAGE 1 =================
__global__ void k_qs(const float* __restrict__ x, const float* __restrict__ Wq_s,
                     float* __restrict__ ws) {
  int c = blockIdx.x, t = threadIdx.x;
  __shared__ float xl[E_];
  xl[t] = x[(size_t)c * E_ + t];
  __syncthreads();
  float s = 0.f;
#pragma unroll 8
  for (int k = 0; k < E_; ++k) s += xl[k] * Wq_s[(size_t)k * E_ + t];
  ws[o_qs + (size_t)c * E_ + t] = s * 0.17677669529663687f;
}

__global__ void k_p(const float* __restrict__ Wk_s, float* __restrict__ ws) {
  int h = blockIdx.x, c = blockIdx.y, t = threadIdx.x;
  __shared__ float q[D_];
  if (t < D_) q[t] = ws[o_qs + (size_t)c * E_ + h * D_ + t];
  __syncthreads();
  const float* wrow = &Wk_s[(size_t)t * E_ + h * D_];
  float s = 0.f;
#pragma unroll
  for (int d = 0; d < D_; d += 4) {
    float4 w = *(const float4*)&wrow[d];
    s += w.x * q[d] + w.y * q[d + 1] + w.z * q[d + 2] + w.w * q[d + 3];
  }
  ws[o_p + ((size_t)c * H_ + h) * E_ + t] = s;
}

__global__ void k_logits(const float* __restrict__ x, float* __restrict__ ws) {
  int c = blockIdx.x, t = threadIdx.x;
  __shared__ float Pl[H_ * E_];
  for (int i = t; i < H_ * E_; i += R_) Pl[i] = ws[o_p + (size_t)c * H_ * E_ + i];
  __syncthreads();
  const float* xr = &x[((size_t)t * C_ + c) * E_];
  float acc[H_];
#pragma unroll
  for (int h = 0; h < H_; ++h) acc[h] = 0.f;
  for (int k = 0; k < E_; k += 4) {
    float4 v = *(const float4*)&xr[k];
#pragma unroll
    for (int h = 0; h < H_; ++h) {
      float4 p = *(const float4*)&Pl[h * E_ + k];
      acc[h] += v.x * p.x + v.y * p.y + v.z * p.z + v.w * p.w;
    }
  }
#pragma unroll
  for (int h = 0; h < H_; ++h)
    ws[o_logits + ((size_t)c * H_ + h) * R_ + t] = acc[h];
}

__global__ void k_softmax_r(const int* __restrict__ seq_mask, float* __restrict__ ws) {
  int h = blockIdx.x, c = blockIdx.y, t = threadIdx.x;
  int lane = t & 63, wid = t >> 6;
  float v = ws[o_logits + ((size_t)c * H_ + h) * R_ + t];
  if (seq_mask[t] == 0) v = NEGF;
  __shared__ float red[4];
  float m = waveRedMax(v);
  if (lane == 0) red[wid] = m;
  __syncthreads();
  float mx = fmaxf(fmaxf(red[0], red[1]), fmaxf(red[2], red[3]));
  __syncthreads();
  float e = expf(v - mx);
  float s = waveRedSum(e);
  if (lane == 0) red[wid] = s;
  __syncthreads();
  float sum = red[0] + red[1] + red[2] + red[3];
  const float scal = 0.17677669529663687f / sqrtf((float)C_);
  ws[o_sw + ((size_t)c * H_ + h) * R_ + t] = e / sum * scal;
}

// ---------------- weight transposes ----------------
__global__ void k_cvt_w1(const float* __restrict__ Wq, const float* __restrict__ Wk,
                         unsigned short* __restrict__ Wtb) {
  int n = blockIdx.x, k = threadIdx.x;
  const float* W = (n < 384) ? Wq : Wk;
  int col = (n < 384) ? n : n - 384;
  Wtb[(size_t)n * 384 + k] = bf16h(W[(size_t)k * 384 + col]);
}

__global__ void k_cvt_wv(const float* __restrict__ Wv, unsigned short* __restrict__ Wvh,
                         unsigned short* __restrict__ Wvl) {
  int n = blockIdx.x, k = threadIdx.x;
  float w = Wv[(size_t)k * 384 + n];
  unsigned short h, l;
  split2(w, h, l);
  Wvh[(size_t)n * 384 + k] = h;
  Wvl[(size_t)n * 384 + k] = l;
}

// ---------------- k_proj_mma: Q3b/K3b = bf16(x @ [Wq|Wk]) (+ sw on Q) ----------------
__global__ __launch_bounds__(256) void k_proj_mma(
    const float* __restrict__ x, const unsigned short* __restrict__ Wtb,
    const float* __restrict__ sw, unsigned short* __restrict__ Q3b,
    unsigned short* __restrict__ K3b) {
  MMA_PROLOGUE1
  int n0 = blockIdx.x * 128, m0 = blockIdx.y * 128;
  for (int k0 = 0; k0 < 384; k0 += 32) {
    stage_f32h(x + (size_t)m0 * 384 + k0, 384, aB);
    stage_bf16(Wtb + (size_t)n0 * 384 + k0, 384, bB);
    __syncthreads();
    chunk_mma1(aB, bB, wr, wc, acc);
    __syncthreads();
  }
  int lane = threadIdx.x & 63, id16 = lane & 15, l4 = (lane >> 4) * 4;
#pragma unroll
  for (int mi = 0; mi < 4; ++mi) {
#pragma unroll
    for (int ni = 0; ni < 4; ++ni) {
      int n = n0 + wc * 64 + ni * 16 + id16;
      bool isQ = n < 384;
      int nn = isQ ? n : n - 384;  // THE FIX: was `n & 383` (384 is not 2^k!)
      int hh = nn >> 5, dd = nn & 31;
      int mbase = m0 + wr * 64 + mi * 16 + l4;
      f32x4 a = acc[mi][ni];
      unsigned short* dst = isQ ? Q3b : K3b;
#pragma unroll
      for (int reg = 0; reg < 4; ++reg) {
        int m = mbase + reg;
        int r = m / 384, c = m - r * 384;
        float v = a[reg];
        if (isQ) v *= sw[((size_t)c * 12 + hh) * 256 + r];
        dst[((size_t)(hh * 384 + c)) * 8192 + r * 32 + dd] = bf16h(v);
      }
    }
  }
}

// ---------------- k_qk_mma: QKf[h][i][j] = sum_k Q3b[h][i][k]*K3b[h][j][k] ----------------
__global__ __launch_bounds__(256) void k_qk_mma(
    const unsigned short* __restrict__ Q3b, const unsigned short* __restrict__ K3b,
    float* __restrict__ QKf) {
  MMA_PROLOGUE1
  int n0 = blockIdx.x * 128, m0 = blockIdx.y * 128, h = blockIdx.z;
  const size_t hb = (size_t)h * 384 * 8192;
  for (int k0 = 0; k0 < 8192; k0 += 32) {
    stage_bf16(Q3b + hb + (size_t)m0 * 8192 + k0, 8192, aB);
    stage_bf16(K3b + hb + (size_t)n0 * 8192 + k0, 8192, bB);
    __syncthreads();
    chunk_mma1(aB, bB, wr, wc, acc);
    __syncthreads();
  }
  int lane = threadIdx.x & 63, id16 = lane & 15, l4 = (lane >> 4) * 4;
#pragma unroll
  for (int mi = 0; mi < 4; ++mi)
#pragma unroll
    for (int ni = 0; ni < 4; ++ni) {
      int i0 = m0 + wr * 64 + mi * 16 + l4;
      int j = n0 + wc * 64 + ni * 16 + id16;
      f32x4 a = acc[mi][ni];
#pragma unroll
      for (int reg = 0; reg < 4; ++reg)
        QKf[((size_t)h * 384 + i0 + reg) * 384 + j] = a[reg];
    }
}

// ---------------- k_softmax_j (R1 verbatim, in place at o_attn) ----------------
__global__ void k_softmax_j(const int* __restrict__ res_mask, float* __restrict__ ws) {
  int i = blockIdx.x, h = blockIdx.y, t = threadIdx.x;
  int lane = t & 63, wid = t >> 6;
  size_t base = o_attn + ((size_t)h * C_ + i) * C_;
  float v = ws[base + t];
  if ((res_mask[i] * res_mask[t]) == 0) v = NEGF;
  __shared__ float red[6];
  float m = waveRedMax(v);
  if (lane == 0) red[wid] = m;
  __syncthreads();
  float mx = red[0];
#pragma unroll
  for (int w = 1; w < 6; ++w) mx = fmaxf(mx, red[w]);
  __syncthreads();
  float e = expf(v - mx);
  float s = waveRedSum(e);
  if (lane == 0) red[wid] = s;
  __syncthreads();
  float sum = 0.f;
#pragma unroll
  for (int w = 0; w < 6; ++w) sum += red[w];
  ws[base + t] = e / sum;
}

// ================= R5-VERBATIM MFMA V + PV =================
__global__ __launch_bounds__(256) void k_v_mma(
    const float* __restrict__ x, const unsigned short* __restrict__ Wvh,
    const unsigned short* __restrict__ Wvl, unsigned short* __restrict__ V3h,
    unsigned short* __restrict__ V3l) {
  MMA_PROLOGUE
  int n0 = blockIdx.x * 128, m0 = blockIdx.y * 128;
  for (int k0 = 0; k0 < 384; k0 += 32) {
    stage_f32(x + (size_t)m0 * 384 + k0, 384, aH, aL);
    stage_bf16(Wvh + (size_t)n0 * 384 + k0, 384, bH);
    stage_bf16(Wvl + (size_t)n0 * 384 + k0, 384, bL);
    __syncthreads();
    chunk_mma(aH, aL, bH, bL, wr, wc, acc);
    __syncthreads();
  }
  int lane = threadIdx.x & 63, id16 = lane & 15, l4 = (lane >> 4) * 4;
#pragma unroll
  for (int mi = 0; mi < 4; ++mi) {
#pragma unroll
    for (int ni = 0; ni < 4; ++ni) {
      int n = n0 + wc * 64 + ni * 16 + id16;
      int hh = n >> 5, dd = n & 31;
      int mbase = m0 + wr * 64 + mi * 16 + l4;
      int r = mbase / 384, c0 = mbase - r * 384;
      f32x4 a = acc[mi][ni];
      u16x4 hv, lv;
#pragma unroll
      for (int reg = 0; reg < 4; ++reg) {
        unsigned short hb, lb;
        split2(a[reg], hb, lb);
        hv[reg] = hb;
        lv[reg] = lb;
      }
      size_t off = ((size_t)hh * 8192 + r * 32 + dd) * 384 + c0;
      *(u16x4*)(V3h + off) = hv;
      *(u16x4*)(V3l + off) = lv;
    }
  }
}

__global__ __launch_bounds__(256) void k_out_mma(
    const float* __restrict__ ws_c, const unsigned short* __restrict__ V3h,
    const unsigned short* __restrict__ V3l, float* __restrict__ out) {
  MMA_PROLOGUE
  int n0 = blockIdx.x * 128, m0 = blockIdx.y * 128, h = blockIdx.z;
  const float* att = ws_c + o_attn + (size_t)h * 384 * 384;
  const unsigned short* Bb = V3h + (size_t)h * 8192 * 384;
  const unsigned short* Bl_ = V3l + (size_t)h * 8192 * 384;
  for (int k0 = 0; k0 < 384; k0 += 32) {
    stage_f32(att + (size_t)m0 * 384 + k0, 384, aH, aL);
    stage_bf16(Bb + (size_t)n0 * 384 + k0, 384, bH);
    stage_bf16(Bl_ + (size_t)n0 * 384 + k0, 384, bL);
    __syncthreads();
    chunk_mma(aH, aL, bH, bL, wr, wc, acc);
    __syncthreads();
  }
  int lane = threadIdx.x & 63, id16 = lane & 15, l4 = (lane >> 4) * 4;
#pragma unroll
  for (int mi = 0; mi < 4; ++mi)
#pragma unroll
    for (int ni = 0; ni < 4; ++ni) {
      int i0 = m0 + wr * 64 + mi * 16 + l4;
      int n = n0 + wc * 64 + ni * 16 + id16;
      int r = n >> 5, d = n & 31;
      f32x4 a = acc[mi][ni];
#pragma unroll
      for (int reg = 0; reg < 4; ++reg)
        out[(((size_t)r * 384 + i0 + reg) * 12 + h) * 32 + d] = a[reg];
    }
}

extern "C" void kernel_launch(void* const* d_in, const int* in_sizes, int n_in,
                              void* d_out, int out_size, void* d_ws, size_t ws_size,
                              hipStream_t stream) {
  const float* x = (const float*)d_in[0];
  const float* Wq = (const float*)d_in[1];
  const float* Wk = (const float*)d_in[2];
  const float* Wv = (const float*)d_in[3];
  const float* Wq_s = (const float*)d_in[4];
  const float* Wk_s = (const float*)d_in[5];
  const int* res_mask = (const int*)d_in[6];
  const int* seq_mask = (const int*)d_in[7];
  float* ws = (float*)d_ws;
  char* wsb = (char*)d_ws;
  float* out = (float*)d_out;

  unsigned short* Wvh = (unsigned short*)(wsb + ob_wvh);
  unsigned short* Wvl = (unsigned short*)(wsb + ob_wvl);
  unsigned short* Wtb = (unsigned short*)(wsb + ob_wtb);
  unsigned short* Q3b = (unsigned short*)(wsb + ob_q3b);
  unsigned short* K3b = (unsigned short*)(wsb + ob_k3b);
  unsigned short* V3h = (unsigned short*)(wsb + ob_v3h);
  unsigned short* V3l = (unsigned short*)(wsb + ob_v3l);
  float* QKf = ws + o_attn;

  hipLaunchKernelGGL(k_qs, dim3(C_), dim3(E_), 0, stream, x, Wq_s, ws);
  hipLaunchKernelGGL(k_p, dim3(H_, C_), dim3(E_), 0, stream, Wk_s, ws);
  hipLaunchKernelGGL(k_logits, dim3(C_), dim3(R_), 0, stream, x, ws);
  hipLaunchKernelGGL(k_softmax_r, dim3(H_, C_), dim3(R_), 0, stream, seq_mask, ws);
  hipLaunchKernelGGL(k_cvt_w1, dim3(768), dim3(384), 0, stream, Wq, Wk, Wtb);
  hipLaunchKernelGGL(k_cvt_wv, dim3(384), dim3(384), 0, stream, Wv, Wvh, Wvl);
  hipLaunchKernelGGL(k_proj_mma, dim3(6, 768), dim3(256), 0, stream, x, Wtb, ws + o_sw,
                     Q3b, K3b);
  hipLaunchKernelGGL(k_qk_mma, dim3(3, 3, 12), dim3(256), 0, stream, Q3b, K3b, QKf);
  hipLaunchKernelGGL(k_softmax_j, dim3(C_, H_), dim3(C_), 0, stream, res_mask, ws);
  hipLaunchKernelGGL(k_v_mma, dim3(3, 768), dim3(256), 0, stream, x, Wvh, Wvl, V3h, V3l);
  hipLaunchKernelGGL(k_out_mma, dim3(64, 3, 12), dim3(256), 0, stream, ws, V3h, V3l, out);
}

// Round 11
// 654.650 us; speedup vs baseline: 4.0851x; 1.3203x over previous
//
#include <hip/hip_runtime.h>
#include <math.h>

#define DEV_INLINE __device__ __forceinline__

constexpr int R_ = 256, C_ = 384, E_ = 384, H_ = 12, D_ = 32;
constexpr float NEGF = -3.402823466e38f;

typedef __attribute__((ext_vector_type(4))) float f32x4;
typedef __attribute__((ext_vector_type(8))) short short8;
typedef __attribute__((ext_vector_type(4))) unsigned short u16x4;

// ---------------- workspace layout ----------------
constexpr size_t o_qs     = 0;                                 // C*E
constexpr size_t o_p      = o_qs + (size_t)C_ * E_;            // C*H*E
constexpr size_t o_logits = o_p + (size_t)C_ * H_ * E_;        // C*H*R
constexpr size_t o_sw     = o_logits + (size_t)C_ * H_ * R_;   // C*H*R
constexpr size_t o_attn   = o_sw + (size_t)C_ * H_ * R_;       // H*C*C (QKf->attn in place)
constexpr size_t o_q3     = o_attn + (size_t)H_ * C_ * C_;     // = 6,045,696 floats
// byte overlays — each big region is 37,748,736 bf16 ELEMENTS = 75,497,472 BYTES.
constexpr size_t SZBIG  = 75497472;                  // bytes!
constexpr size_t ob_wtb = o_logits * 4;              // 884,736 B (o_logits dead after softmax_r)
constexpr size_t ob_q3b = o_q3 * 4;                  // 24,182,784
constexpr size_t ob_k3b = ob_q3b + SZBIG;            // 99,680,256
constexpr size_t ob_v3b = ob_k3b + SZBIG;            // 175,177,728  (R10 BUG: was sized 37.7MB = element count)
constexpr size_t ob_xb  = ob_v3b + SZBIG;            // 250,675,200; ends 326,172,672 == R1's proven footprint

// ---------------- helpers ----------------
DEV_INLINE unsigned short bf16h(float x) {
  unsigned int u = __builtin_bit_cast(unsigned int, x);
  unsigned int r = (u + 0x7FFFu + ((u >> 16) & 1u)) >> 16;
  return (unsigned short)r;
}
DEV_INLINE float waveRedMax(float v) {
#pragma unroll
  for (int o = 32; o > 0; o >>= 1) v = fmaxf(v, __shfl_down(v, o));
  return v;
}
DEV_INLINE float waveRedSum(float v) {
#pragma unroll
  for (int o = 32; o > 0; o >>= 1) v += __shfl_down(v, o);
  return v;
}

// ---------------- MFMA tile machinery (128x32 tiles, LROW=40; verified R5/R9) ----------------
constexpr int LROW = 40;
constexpr int LDS_TILE = 128 * LROW;

DEV_INLINE void stage_f32h(const float* __restrict__ src, int lda, unsigned short* dH) {
  int t = threadIdx.x;
  int row = t >> 1, half = t & 1;
  const float* p = src + (size_t)row * lda + half * 16;
  unsigned short h[16];
#pragma unroll
  for (int i = 0; i < 4; ++i) {
    float4 f = *(const float4*)(p + i * 4);
    h[i * 4 + 0] = bf16h(f.x);
    h[i * 4 + 1] = bf16h(f.y);
    h[i * 4 + 2] = bf16h(f.z);
    h[i * 4 + 3] = bf16h(f.w);
  }
  unsigned short* db = dH + row * LROW + half * 16;
  *(short8*)(db + 0) = *(const short8*)&h[0];
  *(short8*)(db + 8) = *(const short8*)&h[8];
}

DEV_INLINE void stage_bf16(const unsigned short* __restrict__ src, int lda,
                           unsigned short* d) {
  int t = threadIdx.x;
  int row = t >> 1, half = t & 1;
  const unsigned short* p = src + (size_t)row * lda + half * 16;
  short8 v0 = *(const short8*)(p);
  short8 v1 = *(const short8*)(p + 8);
  unsigned short* db = d + row * LROW + half * 16;
  *(short8*)(db + 0) = v0;
  *(short8*)(db + 8) = v1;
}

DEV_INLINE void chunk_mma1(const unsigned short* aB, const unsigned short* bB,
                           int wr, int wc, f32x4 acc[4][4]) {
  int lane = threadIdx.x & 63;
  int id16 = lane & 15, g = lane >> 4;
  short8 A[4], B[4];
#pragma unroll
  for (int mi = 0; mi < 4; ++mi) {
    int row = wr * 64 + mi * 16 + id16;
    A[mi] = *(const short8*)(aB + row * LROW + (g << 3));
  }
#pragma unroll
  for (int ni = 0; ni < 4; ++ni) {
    int col = wc * 64 + ni * 16 + id16;
    B[ni] = *(const short8*)(bB + col * LROW + (g << 3));
  }
#pragma unroll
  for (int mi = 0; mi < 4; ++mi)
#pragma unroll
    for (int ni = 0; ni < 4; ++ni)
      acc[mi][ni] = __builtin_amdgcn_mfma_f32_16x16x32_bf16(A[mi], B[ni], acc[mi][ni], 0, 0, 0);
}

#define MMA_PROLOGUE1                                       \
  __shared__ unsigned short aB[LDS_TILE], bB[LDS_TILE];     \
  int wave = threadIdx.x >> 6, wr = wave >> 1, wc = wave & 1; \
  f32x4 acc[4][4];                                          \
  _Pragma("unroll") for (int mi = 0; mi < 4; ++mi)          \
  _Pragma("unroll") for (int ni = 0; ni < 4; ++ni)          \
      acc[mi][ni] = (f32x4){0.f, 0.f, 0.f, 0.f};

// ================= R1-VERBATIM STAGE 1 =================
__global__ void k_qs(const float* __restrict__ x, const float* __restrict__ Wq_s,
                     float* __restrict__ ws) {
  int c = blockIdx.x, t = threadIdx.x;
  __shared__ float xl[E_];
  xl[t] = x[(size_t)c * E_ + t];
  __syncthreads();
  float s = 0.f;
#pragma unroll 8
  for (int k = 0; k < E_; ++k) s += xl[k] * Wq_s[(size_t)k * E_ + t];
  ws[o_qs + (size_t)c * E_ + t] = s * 0.17677669529663687f;
}

__global__ void k_p(const float* __restrict__ Wk_s, float* __restrict__ ws) {
  int h = blockIdx.x, c = blockIdx.y, t = threadIdx.x;
  __shared__ float q[D_];
  if (t < D_) q[t] = ws[o_qs + (size_t)c * E_ + h * D_ + t];
  __syncthreads();
  const float* wrow = &Wk_s[(size_t)t * E_ + h * D_];
  float s = 0.f;
#pragma unroll
  for (int d = 0; d < D_; d += 4) {
    float4 w = *(const float4*)&wrow[d];
    s += w.x * q[d] + w.y * q[d + 1] + w.z * q[d + 2] + w.w * q[d + 3];
  }
  ws[o_p + ((size_t)c * H_ + h) * E_ + t] = s;
}

__global__ void k_logits(const float* __restrict__ x, float* __restrict__ ws) {
  int c = blockIdx.x, t = threadIdx.x;
  __shared__ float Pl[H_ * E_];
  for (int i = t; i < H_ * E_; i += R_) Pl[i] = ws[o_p + (size_t)c * H_ * E_ + i];
  __syncthreads();
  const float* xr = &x[((size_t)t * C_ + c) * E_];
  float acc[H_];
#pragma unroll
  for (int h = 0; h < H_; ++h) acc[h] = 0.f;
  for (int k = 0; k < E_; k += 4) {
    float4 v = *(const float4*)&xr[k];
#pragma unroll
    for (int h = 0; h < H_; ++h) {
      float4 p = *(const float4*)&Pl[h * E_ + k];
      acc[h] += v.x * p.x + v.y * p.y + v.z * p.z + v.w * p.w;
    }
  }
#pragma unroll
  for (int h = 0; h < H_; ++h)
    ws[o_logits + ((size_t)c * H_ + h) * R_ + t] = acc[h];
}

__global__ void k_softmax_r(const int* __restrict__ seq_mask, float* __restrict__ ws) {
  int h = blockIdx.x, c = blockIdx.y, t = threadIdx.x;
  int lane = t & 63, wid = t >> 6;
  float v = ws[o_logits + ((size_t)c * H_ + h) * R_ + t];
  if (seq_mask[t] == 0) v = NEGF;
  __shared__ float red[4];
  float m = waveRedMax(v);
  if (lane == 0) red[wid] = m;
  __syncthreads();
  float mx = fmaxf(fmaxf(red[0], red[1]), fmaxf(red[2], red[3]));
  __syncthreads();
  float e = expf(v - mx);
  float s = waveRedSum(e);
  if (lane == 0) red[wid] = s;
  __syncthreads();
  float sum = red[0] + red[1] + red[2] + red[3];
  const float scal = 0.17677669529663687f / sqrtf((float)C_);
  ws[o_sw + ((size_t)c * H_ + h) * R_ + t] = e / sum * scal;
}

// ---------------- conversions ----------------
__global__ void k_cvt_x(const float* __restrict__ x, unsigned short* __restrict__ xb) {
  size_t i = ((size_t)blockIdx.x * 256 + threadIdx.x) * 16;
  unsigned short h[16];
#pragma unroll
  for (int j = 0; j < 4; ++j) {
    float4 f = *(const float4*)&x[i + j * 4];
    h[j * 4 + 0] = bf16h(f.x);
    h[j * 4 + 1] = bf16h(f.y);
    h[j * 4 + 2] = bf16h(f.z);
    h[j * 4 + 3] = bf16h(f.w);
  }
  *(short8*)&xb[i] = *(const short8*)&h[0];
  *(short8*)&xb[i + 8] = *(const short8*)&h[8];
}

__global__ void k_cvt_w(const float* __restrict__ Wq, const float* __restrict__ Wk,
                        const float* __restrict__ Wv, unsigned short* __restrict__ Wtb) {
  int n = blockIdx.x, k = threadIdx.x;
  const float* W;
  int col;
  if (n < 384)      { W = Wq; col = n; }
  else if (n < 768) { W = Wk; col = n - 384; }
  else              { W = Wv; col = n - 768; }
  Wtb[(size_t)n * 384 + k] = bf16h(W[(size_t)k * 384 + col]);
}

// ---------------- k_proj_all: Q3b/K3b/V3b = bf16(x @ [Wq|Wk|Wv]) (+ sw on Q) ----------------
__global__ __launch_bounds__(256) void k_proj_all(
    const unsigned short* __restrict__ xb, const unsigned short* __restrict__ Wtb,
    const float* __restrict__ sw, unsigned short* __restrict__ Q3b,
    unsigned short* __restrict__ K3b, unsigned short* __restrict__ V3b) {
  MMA_PROLOGUE1
  int Dd = blockIdx.x;                       // 6912 blocks; 6912/8 = 864 -> bijective
  int L = (Dd & 7) * 864 + (Dd >> 3);
  int bm = L / 9, bn = L - bm * 9;
  int n0 = bn * 128, m0 = bm * 128;
  for (int k0 = 0; k0 < 384; k0 += 32) {
    stage_bf16(xb + (size_t)m0 * 384 + k0, 384, aB);
    stage_bf16(Wtb + (size_t)n0 * 384 + k0, 384, bB);
    __syncthreads();
    chunk_mma1(aB, bB, wr, wc, acc);
    __syncthreads();
  }
  int lane = threadIdx.x & 63, id16 = lane & 15, l4 = (lane >> 4) * 4;
  if (bn < 6) {  // Q or K (boundary 384 is a multiple of 128 -> block-uniform Q/K split per n)
#pragma unroll
    for (int mi = 0; mi < 4; ++mi) {
#pragma unroll
      for (int ni = 0; ni < 4; ++ni) {
        int n = n0 + wc * 64 + ni * 16 + id16;
        bool isQ = n < 384;
        int nn = isQ ? n : n - 384;
        int hh = nn >> 5, dd = nn & 31;
        int mbase = m0 + wr * 64 + mi * 16 + l4;
        f32x4 a = acc[mi][ni];
        unsigned short* dst = isQ ? Q3b : K3b;
#pragma unroll
        for (int reg = 0; reg < 4; ++reg) {
          int m = mbase + reg;
          int r = m / 384, c = m - r * 384;
          float v = a[reg];
          if (isQ) v *= sw[((size_t)c * 12 + hh) * 256 + r];
          dst[((size_t)(hh * 384 + c)) * 8192 + r * 32 + dd] = bf16h(v);
        }
      }
    }
  } else {  // V: V3b[h][r*32+d][c]
#pragma unroll
    for (int mi = 0; mi < 4; ++mi) {
#pragma unroll
      for (int ni = 0; ni < 4; ++ni) {
        int nv = n0 + wc * 64 + ni * 16 + id16 - 768;
        int hh = nv >> 5, dd = nv & 31;
        int mbase = m0 + wr * 64 + mi * 16 + l4;
        int r = mbase / 384, c0 = mbase - r * 384;  // 4 regs = 4 consecutive c
        f32x4 a = acc[mi][ni];
        u16x4 hv;
#pragma unroll
        for (int reg = 0; reg < 4; ++reg) hv[reg] = bf16h(a[reg]);
        *(u16x4*)(V3b + ((size_t)hh * 8192 + r * 32 + dd) * 384 + c0) = hv;
      }
    }
  }
}

// ---------------- k_qk_mma: 64x64 tiles, BK=64 -> 432 blocks ----------------
constexpr int LROW2 = 72;

DEV_INLINE void stage64(const unsigned short* __restrict__ src, int lda,
                        unsigned short* d) {
  int t = threadIdx.x;
  int row = t >> 2, q = t & 3;
  const unsigned short* p = src + (size_t)row * lda + q * 16;
  short8 v0 = *(const short8*)(p);
  short8 v1 = *(const short8*)(p + 8);
  unsigned short* db = d + row * LROW2 + q * 16;
  *(short8*)(db + 0) = v0;
  *(short8*)(db + 8) = v1;
}

__global__ __launch_bounds__(256) void k_qk_mma(
    const unsigned short* __restrict__ Q3b, const unsigned short* __restrict__ K3b,
    float* __restrict__ QKf) {
  __shared__ unsigned short aB[64 * LROW2], bB[64 * LROW2];
  int Dd = blockIdx.x;                       // 432 blocks, 432/8 = 54 -> bijective
  int L = (Dd & 7) * 54 + (Dd >> 3);
  int h = L / 36, rem = L - h * 36, bi = rem / 6, bj = rem - bi * 6;
  int wave = threadIdx.x >> 6, wr = wave >> 1, wc = wave & 1;
  int lane = threadIdx.x & 63, id16 = lane & 15, g = lane >> 4;
  f32x4 acc[2][2];
#pragma unroll
  for (int mi = 0; mi < 2; ++mi)
#pragma unroll
    for (int ni = 0; ni < 2; ++ni) acc[mi][ni] = (f32x4){0.f, 0.f, 0.f, 0.f};
  const size_t hb = (size_t)h * 384 * 8192;
  for (int k0 = 0; k0 < 8192; k0 += 64) {
    stage64(Q3b + hb + (size_t)(bi * 64) * 8192 + k0, 8192, aB);
    stage64(K3b + hb + (size_t)(bj * 64) * 8192 + k0, 8192, bB);
    __syncthreads();
    short8 A[2][2], B[2][2];
#pragma unroll
    for (int mi = 0; mi < 2; ++mi) {
      int row = wr * 32 + mi * 16 + id16;
#pragma unroll
      for (int kk = 0; kk < 2; ++kk)
        A[mi][kk] = *(const short8*)(aB + row * LROW2 + kk * 32 + (g << 3));
    }
#pragma unroll
    for (int ni = 0; ni < 2; ++ni) {
      int col = wc * 32 + ni * 16 + id16;
#pragma unroll
      for (int kk = 0; kk < 2; ++kk)
        B[ni][kk] = *(const short8*)(bB + col * LROW2 + kk * 32 + (g << 3));
    }
#pragma unroll
    for (int mi = 0; mi < 2; ++mi)
#pragma unroll
      for (int ni = 0; ni < 2; ++ni) {
        acc[mi][ni] = __builtin_amdgcn_mfma_f32_16x16x32_bf16(A[mi][0], B[ni][0], acc[mi][ni], 0, 0, 0);
        acc[mi][ni] = __builtin_amdgcn_mfma_f32_16x16x32_bf16(A[mi][1], B[ni][1], acc[mi][ni], 0, 0, 0);
      }
    __syncthreads();
  }
  int l4 = (lane >> 4) * 4;
#pragma unroll
  for (int mi = 0; mi < 2; ++mi)
#pragma unroll
    for (int ni = 0; ni < 2; ++ni) {
      int i0 = bi * 64 + wr * 32 + mi * 16 + l4;
      int j = bj * 64 + wc * 32 + ni * 16 + id16;
      f32x4 a = acc[mi][ni];
#pragma unroll
      for (int reg = 0; reg < 4; ++reg)
        QKf[((size_t)h * 384 + i0 + reg) * 384 + j] = a[reg];
    }
}

// ---------------- k_softmax_j (R1 verbatim, in place at o_attn) ----------------
__global__ void k_softmax_j(const int* __restrict__ res_mask, float* __restrict__ ws) {
  int i = blockIdx.x, h = blockIdx.y, t = threadIdx.x;
  int lane = t & 63, wid = t >> 6;
  size_t base = o_attn + ((size_t)h * C_ + i) * C_;
  float v = ws[base + t];
  if ((res_mask[i] * res_mask[t]) == 0) v = NEGF;
  __shared__ float red[6];
  float m = waveRedMax(v);
  if (lane == 0) red[wid] = m;
  __syncthreads();
  float mx = red[0];
#pragma unroll
  for (int w = 1; w < 6; ++w) mx = fmaxf(mx, red[w]);
  __syncthreads();
  float e = expf(v - mx);
  float s = waveRedSum(e);
  if (lane == 0) red[wid] = s;
  __syncthreads();
  float sum = 0.f;
#pragma unroll
  for (int w = 0; w < 6; ++w) sum += red[w];
  ws[base + t] = e / sum;
}

// ---------------- k_out_mma: out = attn @ V3b ----------------
__global__ __launch_bounds__(256) void k_out_mma(
    const float* __restrict__ ws_c, const unsigned short* __restrict__ V3b,
    float* __restrict__ out) {
  MMA_PROLOGUE1
  int Dd = blockIdx.x;                        // 2304 blocks, 2304/8 = 288 -> bijective
  int L = (Dd & 7) * 288 + (Dd >> 3);
  int bn = L % 64, bm = (L / 64) % 3, h = L / 192;
  int n0 = bn * 128, m0 = bm * 128;
  const float* att = ws_c + o_attn + (size_t)h * 384 * 384;
  const unsigned short* Bb = V3b + (size_t)h * 8192 * 384;
  for (int k0 = 0; k0 < 384; k0 += 32) {
    stage_f32h(att + (size_t)m0 * 384 + k0, 384, aB);
    stage_bf16(Bb + (size_t)n0 * 384 + k0, 384, bB);
    __syncthreads();
    chunk_mma1(aB, bB, wr, wc, acc);
    __syncthreads();
  }
  int lane = threadIdx.x & 63, id16 = lane & 15, l4 = (lane >> 4) * 4;
#pragma unroll
  for (int mi = 0; mi < 4; ++mi)
#pragma unroll
    for (int ni = 0; ni < 4; ++ni) {
      int i0 = m0 + wr * 64 + mi * 16 + l4;
      int n = n0 + wc * 64 + ni * 16 + id16;  // rd index
      int r = n >> 5, d = n & 31;
      f32x4 a = acc[mi][ni];
#pragma unroll
      for (int reg = 0; reg < 4; ++reg)
        out[(((size_t)r * 384 + i0 + reg) * 12 + h) * 32 + d] = a[reg];
    }
}

extern "C" void kernel_launch(void* const* d_in, const int* in_sizes, int n_in,
                              void* d_out, int out_size, void* d_ws, size_t ws_size,
                              hipStream_t stream) {
  const float* x = (const float*)d_in[0];
  const float* Wq = (const float*)d_in[1];
  const float* Wk = (const float*)d_in[2];
  const float* Wv = (const float*)d_in[3];
  const float* Wq_s = (const float*)d_in[4];
  const float* Wk_s = (const float*)d_in[5];
  const int* res_mask = (const int*)d_in[6];
  const int* seq_mask = (const int*)d_in[7];
  float* ws = (float*)d_ws;
  char* wsb = (char*)d_ws;
  float* out = (float*)d_out;

  unsigned short* Wtb = (unsigned short*)(wsb + ob_wtb);
  unsigned short* Q3b = (unsigned short*)(wsb + ob_q3b);
  unsigned short* K3b = (unsigned short*)(wsb + ob_k3b);
  unsigned short* V3b = (unsigned short*)(wsb + ob_v3b);
  unsigned short* xb  = (unsigned short*)(wsb + ob_xb);

  float* QKf = ws + o_attn;

  hipLaunchKernelGGL(k_cvt_x, dim3(9216), dim3(256), 0, stream, x, xb);
  hipLaunchKernelGGL(k_qs, dim3(C_), dim3(E_), 0, stream, x, Wq_s, ws);
  hipLaunchKernelGGL(k_p, dim3(H_, C_), dim3(E_), 0, stream, Wk_s, ws);
  hipLaunchKernelGGL(k_logits, dim3(C_), dim3(R_), 0, stream, x, ws);
  hipLaunchKernelGGL(k_softmax_r, dim3(H_, C_), dim3(R_), 0, stream, seq_mask, ws);
  hipLaunchKernelGGL(k_cvt_w, dim3(1152), dim3(384), 0, stream, Wq, Wk, Wv, Wtb);
  hipLaunchKernelGGL(k_proj_all, dim3(6912), dim3(256), 0, stream, xb, Wtb, ws + o_sw,
                     Q3b, K3b, V3b);
  hipLaunchKernelGGL(k_qk_mma, dim3(432), dim3(256), 0, stream, Q3b, K3b, QKf);
  hipLaunchKernelGGL(k_softmax_j, dim3(C_, H_), dim3(C_), 0, stream, res_mask, ws);
  hipLaunchKernelGGL(k_out_mma, dim3(2304), dim3(256), 0, stream, ws, V3b, out);
}

// Round 12
// 505.990 us; speedup vs baseline: 5.2853x; 1.2938x over previous
//
#include <hip/hip_runtime.h>
#include <math.h>
#include <stdint.h>

#define DEV_INLINE __device__ __forceinline__

constexpr int R_ = 256, C_ = 384, E_ = 384, H_ = 12, D_ = 32;
constexpr float NEGF = -3.402823466e38f;

typedef __attribute__((ext_vector_type(4))) float f32x4;
typedef __attribute__((ext_vector_type(8))) short short8;
typedef __attribute__((ext_vector_type(4))) unsigned short u16x4;

// ---------------- workspace layout ----------------
constexpr size_t o_qs     = 0;                                 // C*E
constexpr size_t o_p      = o_qs + (size_t)C_ * E_;            // C*H*E (swT overlays after k_logits)
constexpr size_t o_logits = o_p + (size_t)C_ * H_ * E_;        // C*H*R
constexpr size_t o_sw     = o_logits + (size_t)C_ * H_ * R_;   // C*H*R
constexpr size_t o_attn   = o_sw + (size_t)C_ * H_ * R_;       // H*C*C (QKf0 -> attn in place)
constexpr size_t o_q3     = o_attn + (size_t)H_ * C_ * C_;
// byte overlays (each big region = 75,497,472 BYTES):
constexpr size_t SZBIG  = 75497472;
constexpr size_t ob_wtb = o_logits * 4;              // Wtb (o_logits dead after softmax_r)
constexpr size_t ob_q3b = o_q3 * 4;                  // 24,182,784 (attnb overlays after k_qk)
constexpr size_t ob_k3b = ob_q3b + SZBIG;            // 99,680,256
constexpr size_t ob_v3b = ob_k3b + SZBIG;            // 175,177,728
constexpr size_t ob_xb  = ob_v3b + SZBIG;            // 250,675,200 (QKf1 overlays after proj); ends 326,172,672

// ---------------- helpers ----------------
DEV_INLINE unsigned short bf16h(float x) {
  unsigned int u = __builtin_bit_cast(unsigned int, x);
  unsigned int r = (u + 0x7FFFu + ((u >> 16) & 1u)) >> 16;
  return (unsigned short)r;
}
DEV_INLINE float waveRedMax(float v) {
#pragma unroll
  for (int o = 32; o > 0; o >>= 1) v = fmaxf(v, __shfl_down(v, o));
  return v;
}
DEV_INLINE float waveRedSum(float v) {
#pragma unroll
  for (int o = 32; o > 0; o >>= 1) v += __shfl_down(v, o);
  return v;
}

// ---------------- async global->LDS staging (linear LDS + swizzled source) ----------------
DEV_INLINE void gll16(const void* g, void* l) {
  __builtin_amdgcn_global_load_lds(
      reinterpret_cast<__attribute__((address_space(1))) void*>(
          reinterpret_cast<uintptr_t>(g)),
      reinterpret_cast<__attribute__((address_space(3))) void*>(
          reinterpret_cast<uintptr_t>(l)),
      16, 0, 0);
}

// Stage ROWS x (UPR*8) shorts; lda in shorts. Physical slot qp holds logical
// unit q = qp ^ (row&7); fragment reads apply the same XOR. (G21: linear dest
// + inverse-swizzled source + swizzled read.)
template <int ROWS, int UPR>
DEV_INLINE void stageT(const unsigned short* __restrict__ g, int lda,
                       unsigned short* l) {
  int t = threadIdx.x, w = t >> 6, lane = t & 63;
  constexpr int NI = (ROWS * UPR) / 64;  // total wave-instructions
  constexpr int PW = NI / 4;             // per wave
#pragma unroll
  for (int j = 0; j < PW; ++j) {
    int u0 = (w * PW + j) * 64;
    int u = u0 + lane;
    int row = u / UPR, qp = u % UPR;
    int q = qp ^ (row & 7);
    gll16(g + (size_t)row * lda + q * 8, l + (size_t)u0 * 8);
  }
}

DEV_INLINE short8 fragLd(const unsigned short* base, int row, int q, int rowShorts) {
  int qp = q ^ (row & 7);
  return *(const short8*)(base + row * rowShorts + qp * 8);
}

// ================= R1-VERBATIM STAGE 1 =================
__global__ void k_qs(const float* __restrict__ x, const float* __restrict__ Wq_s,
                     float* __restrict__ ws) {
  int c = blockIdx.x, t = threadIdx.x;
  __shared__ float xl[E_];
  xl[t] = x[(size_t)c * E_ + t];
  __syncthreads();
  float s = 0.f;
#pragma unroll 8
  for (int k = 0; k < E_; ++k) s += xl[k] * Wq_s[(size_t)k * E_ + t];
  ws[o_qs + (size_t)c * E_ + t] = s * 0.17677669529663687f;
}

__global__ void k_p(const float* __restrict__ Wk_s, float* __restrict__ ws) {
  int h = blockIdx.x, c = blockIdx.y, t = threadIdx.x;
  __shared__ float q[D_];
  if (t < D_) q[t] = ws[o_qs + (size_t)c * E_ + h * D_ + t];
  __syncthreads();
  const float* wrow = &Wk_s[(size_t)t * E_ + h * D_];
  float s = 0.f;
#pragma unroll
  for (int d = 0; d < D_; d += 4) {
    float4 w = *(const float4*)&wrow[d];
    s += w.x * q[d] + w.y * q[d + 1] + w.z * q[d + 2] + w.w * q[d + 3];
  }
  ws[o_p + ((size_t)c * H_ + h) * E_ + t] = s;
}

__global__ void k_logits(const float* __restrict__ x, float* __restrict__ ws) {
  int c = blockIdx.x, t = threadIdx.x;
  __shared__ float Pl[H_ * E_];
  for (int i = t; i < H_ * E_; i += R_) Pl[i] = ws[o_p + (size_t)c * H_ * E_ + i];
  __syncthreads();
  const float* xr = &x[((size_t)t * C_ + c) * E_];
  float acc[H_];
#pragma unroll
  for (int h = 0; h < H_; ++h) acc[h] = 0.f;
  for (int k = 0; k < E_; k += 4) {
    float4 v = *(const float4*)&xr[k];
#pragma unroll
    for (int h = 0; h < H_; ++h) {
      float4 p = *(const float4*)&Pl[h * E_ + k];
      acc[h] += v.x * p.x + v.y * p.y + v.z * p.z + v.w * p.w;
    }
  }
#pragma unroll
  for (int h = 0; h < H_; ++h)
    ws[o_logits + ((size_t)c * H_ + h) * R_ + t] = acc[h];
}

// writes sw (original layout) AND swT[h][r][c] (for proj's vectorized loads)
__global__ void k_softmax_r(const int* __restrict__ seq_mask, float* __restrict__ ws) {
  int h = blockIdx.x, c = blockIdx.y, t = threadIdx.x;
  int lane = t & 63, wid = t >> 6;
  float v = ws[o_logits + ((size_t)c * H_ + h) * R_ + t];
  if (seq_mask[t] == 0) v = NEGF;
  __shared__ float red[4];
  float m = waveRedMax(v);
  if (lane == 0) red[wid] = m;
  __syncthreads();
  float mx = fmaxf(fmaxf(red[0], red[1]), fmaxf(red[2], red[3]));
  __syncthreads();
  float e = expf(v - mx);
  float s = waveRedSum(e);
  if (lane == 0) red[wid] = s;
  __syncthreads();
  float sum = red[0] + red[1] + red[2] + red[3];
  const float scal = 0.17677669529663687f / sqrtf((float)C_);
  float r = e / sum * scal;
  ws[o_sw + ((size_t)c * H_ + h) * R_ + t] = r;
  ws[o_p + ((size_t)h * R_ + t) * C_ + c] = r;  // swT over dead o_p
}

// ---------------- conversions ----------------
__global__ void k_cvt_x(const float* __restrict__ x, unsigned short* __restrict__ xb) {
  size_t i = ((size_t)blockIdx.x * 256 + threadIdx.x) * 16;
  unsigned short h[16];
#pragma unroll
  for (int j = 0; j < 4; ++j) {
    float4 f = *(const float4*)&x[i + j * 4];
    h[j * 4 + 0] = bf16h(f.x);
    h[j * 4 + 1] = bf16h(f.y);
    h[j * 4 + 2] = bf16h(f.z);
    h[j * 4 + 3] = bf16h(f.w);
  }
  *(short8*)&xb[i] = *(const short8*)&h[0];
  *(short8*)&xb[i + 8] = *(const short8*)&h[8];
}

__global__ void k_cvt_w(const float* __restrict__ Wq, const float* __restrict__ Wk,
                        const float* __restrict__ Wv, unsigned short* __restrict__ Wtb) {
  int n = blockIdx.x, k = threadIdx.x;
  const float* W;
  int col;
  if (n < 384)      { W = Wq; col = n; }
  else if (n < 768) { W = Wk; col = n - 384; }
  else              { W = Wv; col = n - 768; }
  Wtb[(size_t)n * 384 + k] = bf16h(W[(size_t)k * 384 + col]);
}

// ---------------- k_proj_all: 128x128 tile, BK=64, gll + double buffer ----------------
__global__ __launch_bounds__(256, 2) void k_proj_all(
    const unsigned short* __restrict__ xb, const unsigned short* __restrict__ Wtb,
    const float* __restrict__ swT, unsigned short* __restrict__ Q3b,
    unsigned short* __restrict__ K3b, unsigned short* __restrict__ V3b) {
  __shared__ unsigned short sA[2][128 * 64], sB[2][128 * 64];
  int Dd = blockIdx.x;                       // 6912 blocks; /8 = 864 -> bijective
  int L = (Dd & 7) * 864 + (Dd >> 3);
  int bm = L / 9, bn = L - bm * 9;
  int n0 = bn * 128, m0 = bm * 128;
  int wave = threadIdx.x >> 6, wr = wave >> 1, wc = wave & 1;
  int lane = threadIdx.x & 63, id16 = lane & 15, g = lane >> 4;
  f32x4 acc[4][4];
#pragma unroll
  for (int mi = 0; mi < 4; ++mi)
#pragma unroll
    for (int ni = 0; ni < 4; ++ni) acc[mi][ni] = (f32x4){0.f, 0.f, 0.f, 0.f};

  stageT<128, 8>(xb + (size_t)m0 * 384, 384, sA[0]);
  stageT<128, 8>(Wtb + (size_t)n0 * 384, 384, sB[0]);
  __syncthreads();
  int cur = 0;
  for (int it = 0; it < 6; ++it) {
    if (it < 5) {
      stageT<128, 8>(xb + (size_t)m0 * 384 + (it + 1) * 64, 384, sA[cur ^ 1]);
      stageT<128, 8>(Wtb + (size_t)n0 * 384 + (it + 1) * 64, 384, sB[cur ^ 1]);
    }
    short8 Af[4][2], Bf[4][2];
#pragma unroll
    for (int mi = 0; mi < 4; ++mi) {
      int row = wr * 64 + mi * 16 + id16;
#pragma unroll
      for (int kk = 0; kk < 2; ++kk) Af[mi][kk] = fragLd(sA[cur], row, kk * 4 + g, 64);
    }
#pragma unroll
    for (int ni = 0; ni < 4; ++ni) {
      int col = wc * 64 + ni * 16 + id16;
#pragma unroll
      for (int kk = 0; kk < 2; ++kk) Bf[ni][kk] = fragLd(sB[cur], col, kk * 4 + g, 64);
    }
#pragma unroll
    for (int kk = 0; kk < 2; ++kk)
#pragma unroll
      for (int mi = 0; mi < 4; ++mi)
#pragma unroll
        for (int ni = 0; ni < 4; ++ni)
          acc[mi][ni] = __builtin_amdgcn_mfma_f32_16x16x32_bf16(Af[mi][kk], Bf[ni][kk],
                                                                acc[mi][ni], 0, 0, 0);
    __syncthreads();
    cur ^= 1;
  }

  int l4 = (lane >> 4) * 4;
  int r = bm / 3, cb = (bm % 3) * 128;  // r constant per tile (384 = 3*128)
  if (bn < 6) {  // Q (bn<3) or K — block-uniform since 384%128==0
#pragma unroll
    for (int mi = 0; mi < 4; ++mi) {
      int cbase = cb + wr * 64 + mi * 16 + l4;
#pragma unroll
      for (int ni = 0; ni < 4; ++ni) {
        int n = n0 + wc * 64 + ni * 16 + id16;
        bool isQ = n < 384;
        int nn = isQ ? n : n - 384;
        int hh = nn >> 5, dd = nn & 31;
        f32x4 a = acc[mi][ni];
        if (isQ) {
          float4 sv = *(const float4*)&swT[((size_t)hh * 256 + r) * 384 + cbase];
          a[0] *= sv.x; a[1] *= sv.y; a[2] *= sv.z; a[3] *= sv.w;
        }
        unsigned short* dst = isQ ? Q3b : K3b;
#pragma unroll
        for (int reg = 0; reg < 4; ++reg)
          dst[((size_t)(hh * 384 + cbase + reg)) * 8192 + r * 32 + dd] = bf16h(a[reg]);
      }
    }
  } else {  // V: V3b[h][r*32+d][c]
#pragma unroll
    for (int mi = 0; mi < 4; ++mi) {
      int c0 = cb + wr * 64 + mi * 16 + l4;
#pragma unroll
      for (int ni = 0; ni < 4; ++ni) {
        int nv = n0 + wc * 64 + ni * 16 + id16 - 768;
        int hh = nv >> 5, dd = nv & 31;
        f32x4 a = acc[mi][ni];
        u16x4 hv;
#pragma unroll
        for (int reg = 0; reg < 4; ++reg) hv[reg] = bf16h(a[reg]);
        *(u16x4*)(V3b + ((size_t)hh * 8192 + r * 32 + dd) * 384 + c0) = hv;
      }
    }
  }
}

// ---------------- k_qk_mma: 64x64 tile, BK=128, split-K x2, gll dbuf ----------------
__global__ __launch_bounds__(256, 2) void k_qk_mma(
    const unsigned short* __restrict__ Q3b, const unsigned short* __restrict__ K3b,
    float* __restrict__ QKf0, float* __restrict__ QKf1) {
  __shared__ unsigned short sA[2][64 * 128], sB[2][64 * 128];
  int Dd = blockIdx.x;                       // 864 blocks; /8 = 108 -> bijective
  int L = (Dd & 7) * 108 + (Dd >> 3);
  int kh = L / 432, rem = L - kh * 432;
  int h = rem / 36, r2 = rem - h * 36, bi = r2 / 6, bj = r2 - bi * 6;
  int wave = threadIdx.x >> 6, wr = wave >> 1, wc = wave & 1;
  int lane = threadIdx.x & 63, id16 = lane & 15, g = lane >> 4;
  f32x4 acc[2][2];
#pragma unroll
  for (int mi = 0; mi < 2; ++mi)
#pragma unroll
    for (int ni = 0; ni < 2; ++ni) acc[mi][ni] = (f32x4){0.f, 0.f, 0.f, 0.f};
  const unsigned short* Ab =
      Q3b + (size_t)h * 384 * 8192 + (size_t)(bi * 64) * 8192 + kh * 4096;
  const unsigned short* Bb =
      K3b + (size_t)h * 384 * 8192 + (size_t)(bj * 64) * 8192 + kh * 4096;

  stageT<64, 16>(Ab, 8192, sA[0]);
  stageT<64, 16>(Bb, 8192, sB[0]);
  __syncthreads();
  int cur = 0;
  for (int it = 0; it < 32; ++it) {
    if (it < 31) {
      stageT<64, 16>(Ab + (it + 1) * 128, 8192, sA[cur ^ 1]);
      stageT<64, 16>(Bb + (it + 1) * 128, 8192, sB[cur ^ 1]);
    }
    short8 Af[2][4], Bf[2][4];
#pragma unroll
    for (int mi = 0; mi < 2; ++mi) {
      int row = wr * 32 + mi * 16 + id16;
#pragma unroll
      for (int kk = 0; kk < 4; ++kk) Af[mi][kk] = fragLd(sA[cur], row, kk * 4 + g, 128);
    }
#pragma unroll
    for (int ni = 0; ni < 2; ++ni) {
      int col = wc * 32 + ni * 16 + id16;
#pragma unroll
      for (int kk = 0; kk < 4; ++kk) Bf[ni][kk] = fragLd(sB[cur], col, kk * 4 + g, 128);
    }
#pragma unroll
    for (int kk = 0; kk < 4; ++kk)
#pragma unroll
      for (int mi = 0; mi < 2; ++mi)
#pragma unroll
        for (int ni = 0; ni < 2; ++ni)
          acc[mi][ni] = __builtin_amdgcn_mfma_f32_16x16x32_bf16(Af[mi][kk], Bf[ni][kk],
                                                                acc[mi][ni], 0, 0, 0);
    __syncthreads();
    cur ^= 1;
  }
  int l4 = (lane >> 4) * 4;
  float* dst = kh ? QKf1 : QKf0;
#pragma unroll
  for (int mi = 0; mi < 2; ++mi)
#pragma unroll
    for (int ni = 0; ni < 2; ++ni) {
      int i0 = bi * 64 + wr * 32 + mi * 16 + l4;
      int j = bj * 64 + wc * 32 + ni * 16 + id16;
      f32x4 a = acc[mi][ni];
#pragma unroll
      for (int reg = 0; reg < 4; ++reg)
        dst[((size_t)h * 384 + i0 + reg) * 384 + j] = a[reg];
    }
}

// ---------------- k_softmax_j: sum split-K partials, softmax, emit f32 + bf16 ----------------
__global__ void k_softmax_j(const int* __restrict__ res_mask, float* __restrict__ ws,
                            const float* __restrict__ QKf1,
                            unsigned short* __restrict__ attnb) {
  int i = blockIdx.x, h = blockIdx.y, t = threadIdx.x;
  int lane = t & 63, wid = t >> 6;
  size_t base = o_attn + ((size_t)h * C_ + i) * C_;
  size_t base2 = ((size_t)h * C_ + i) * C_;
  float v = ws[base + t] + QKf1[base2 + t];
  if ((res_mask[i] * res_mask[t]) == 0) v = NEGF;
  __shared__ float red[6];
  float m = waveRedMax(v);
  if (lane == 0) red[wid] = m;
  __syncthreads();
  float mx = red[0];
#pragma unroll
  for (int w = 1; w < 6; ++w) mx = fmaxf(mx, red[w]);
  __syncthreads();
  float e = expf(v - mx);
  float s = waveRedSum(e);
  if (lane == 0) red[wid] = s;
  __syncthreads();
  float sum = 0.f;
#pragma unroll
  for (int w = 0; w < 6; ++w) sum += red[w];
  float pr = e / sum;
  ws[base + t] = pr;
  attnb[base2 + t] = bf16h(pr);
}

// ---------------- k_out_mma: 128x128 tile, BK=64, gll dbuf, A=attnb B=V3b ----------------
__global__ __launch_bounds__(256, 2) void k_out_mma(
    const unsigned short* __restrict__ attnb, const unsigned short* __restrict__ V3b,
    float* __restrict__ out) {
  __shared__ unsigned short sA[2][128 * 64], sB[2][128 * 64];
  int Dd = blockIdx.x;                        // 2304 blocks; /8 = 288 -> bijective
  int L = (Dd & 7) * 288 + (Dd >> 3);
  int bn = L % 64, bm = (L / 64) % 3, h = L / 192;
  int n0 = bn * 128, m0 = bm * 128;
  int wave = threadIdx.x >> 6, wr = wave >> 1, wc = wave & 1;
  int lane = threadIdx.x & 63, id16 = lane & 15, g = lane >> 4;
  f32x4 acc[4][4];
#pragma unroll
  for (int mi = 0; mi < 4; ++mi)
#pragma unroll
    for (int ni = 0; ni < 4; ++ni) acc[mi][ni] = (f32x4){0.f, 0.f, 0.f, 0.f};
  const unsigned short* Ab = attnb + (size_t)h * 384 * 384 + (size_t)m0 * 384;
  const unsigned short* Bb = V3b + (size_t)h * 8192 * 384 + (size_t)n0 * 384;

  stageT<128, 8>(Ab, 384, sA[0]);
  stageT<128, 8>(Bb, 384, sB[0]);
  __syncthreads();
  int cur = 0;
  for (int it = 0; it < 6; ++it) {
    if (it < 5) {
      stageT<128, 8>(Ab + (it + 1) * 64, 384, sA[cur ^ 1]);
      stageT<128, 8>(Bb + (it + 1) * 64, 384, sB[cur ^ 1]);
    }
    short8 Af[4][2], Bf[4][2];
#pragma unroll
    for (int mi = 0; mi < 4; ++mi) {
      int row = wr * 64 + mi * 16 + id16;
#pragma unroll
      for (int kk = 0; kk < 2; ++kk) Af[mi][kk] = fragLd(sA[cur], row, kk * 4 + g, 64);
    }
#pragma unroll
    for (int ni = 0; ni < 4; ++ni) {
      int col = wc * 64 + ni * 16 + id16;
#pragma unroll
      for (int kk = 0; kk < 2; ++kk) Bf[ni][kk] = fragLd(sB[cur], col, kk * 4 + g, 64);
    }
#pragma unroll
    for (int kk = 0; kk < 2; ++kk)
#pragma unroll
      for (int mi = 0; mi < 4; ++mi)
#pragma unroll
        for (int ni = 0; ni < 4; ++ni)
          acc[mi][ni] = __builtin_amdgcn_mfma_f32_16x16x32_bf16(Af[mi][kk], Bf[ni][kk],
                                                                acc[mi][ni], 0, 0, 0);
    __syncthreads();
    cur ^= 1;
  }
  int l4 = (lane >> 4) * 4;
#pragma unroll
  for (int mi = 0; mi < 4; ++mi)
#pragma unroll
    for (int ni = 0; ni < 4; ++ni) {
      int i0 = m0 + wr * 64 + mi * 16 + l4;
      int n = n0 + wc * 64 + ni * 16 + id16;  // rd index
      int r = n >> 5, d = n & 31;
      f32x4 a = acc[mi][ni];
#pragma unroll
      for (int reg = 0; reg < 4; ++reg)
        out[(((size_t)r * 384 + i0 + reg) * 12 + h) * 32 + d] = a[reg];
    }
}

extern "C" void kernel_launch(void* const* d_in, const int* in_sizes, int n_in,
                              void* d_out, int out_size, void* d_ws, size_t ws_size,
                              hipStream_t stream) {
  const float* x = (const float*)d_in[0];
  const float* Wq = (const float*)d_in[1];
  const float* Wk = (const float*)d_in[2];
  const float* Wv = (const float*)d_in[3];
  const float* Wq_s = (const float*)d_in[4];
  const float* Wk_s = (const float*)d_in[5];
  const int* res_mask = (const int*)d_in[6];
  const int* seq_mask = (const int*)d_in[7];
  float* ws = (float*)d_ws;
  char* wsb = (char*)d_ws;
  float* out = (float*)d_out;

  unsigned short* Wtb = (unsigned short*)(wsb + ob_wtb);
  unsigned short* Q3b = (unsigned short*)(wsb + ob_q3b);
  unsigned short* K3b = (unsigned short*)(wsb + ob_k3b);
  unsigned short* V3b = (unsigned short*)(wsb + ob_v3b);
  unsigned short* xb  = (unsigned short*)(wsb + ob_xb);
  unsigned short* attnb = Q3b;              // overlays Q3b (dead after k_qk)
  float* QKf1 = (float*)(wsb + ob_xb);      // overlays xb (dead after proj)
  float* swT = ws + o_p;                    // overlays o_p (dead after k_logits)

  hipLaunchKernelGGL(k_cvt_x, dim3(9216), dim3(256), 0, stream, x, xb);
  hipLaunchKernelGGL(k_qs, dim3(C_), dim3(E_), 0, stream, x, Wq_s, ws);
  hipLaunchKernelGGL(k_p, dim3(H_, C_), dim3(E_), 0, stream, Wk_s, ws);
  hipLaunchKernelGGL(k_logits, dim3(C_), dim3(R_), 0, stream, x, ws);
  hipLaunchKernelGGL(k_softmax_r, dim3(H_, C_), dim3(R_), 0, stream, seq_mask, ws);
  hipLaunchKernelGGL(k_cvt_w, dim3(1152), dim3(384), 0, stream, Wq, Wk, Wv, Wtb);
  hipLaunchKernelGGL(k_proj_all, dim3(6912), dim3(256), 0, stream, xb, Wtb, swT,
                     Q3b, K3b, V3b);
  hipLaunchKernelGGL(k_qk_mma, dim3(864), dim3(256), 0, stream, Q3b, K3b,
                     ws + o_attn, QKf1);
  hipLaunchKernelGGL(k_softmax_j, dim3(C_, H_), dim3(C_), 0, stream, res_mask, ws,
                     QKf1, attnb);
  hipLaunchKernelGGL(k_out_mma, dim3(2304), dim3(256), 0, stream, attnb, V3b, out);
}

// Round 13
// 411.849 us; speedup vs baseline: 6.4934x; 1.2286x over previous
//
#include <hip/hip_runtime.h>
#include <math.h>
#include <stdint.h>

#define DEV_INLINE __device__ __forceinline__

constexpr int R_ = 256, C_ = 384, E_ = 384, H_ = 12, D_ = 32;
constexpr float NEGF = -3.402823466e38f;

typedef __attribute__((ext_vector_type(4))) float f32x4;
typedef __attribute__((ext_vector_type(8))) short short8;
typedef __attribute__((ext_vector_type(4))) unsigned short u16x4;

// ---------------- workspace layout ----------------
constexpr size_t o_qs     = 0;                                 // C*E f32 (qs)
constexpr size_t o_p      = o_qs + (size_t)C_ * E_;            // Pb bf16 overlay (384*16*384*2B < region)
constexpr size_t o_logits = o_p + (size_t)C_ * H_ * E_;        // swT f32 [12][256][384] (exact fit)
constexpr size_t o_sw     = o_logits + (size_t)C_ * H_ * R_;   // (free)
constexpr size_t o_attn   = o_sw + (size_t)C_ * H_ * R_;       // QKf0; Wtb overlays pre-qk
constexpr size_t o_q3     = o_attn + (size_t)H_ * C_ * C_;
constexpr size_t SZBIG  = 75497472;                  // bytes per big region
constexpr size_t ob_q3b = o_q3 * 4;                  // 24,182,784 (attnb overlays after qk)
constexpr size_t ob_k3b = ob_q3b + SZBIG;
constexpr size_t ob_v3b = ob_k3b + SZBIG;
constexpr size_t ob_xb  = ob_v3b + SZBIG;            // (QKf1 overlays after proj); ends 326,172,672

// ---------------- helpers ----------------
DEV_INLINE unsigned short bf16h(float x) {
  unsigned int u = __builtin_bit_cast(unsigned int, x);
  unsigned int r = (u + 0x7FFFu + ((u >> 16) & 1u)) >> 16;
  return (unsigned short)r;
}
DEV_INLINE float waveRedMax(float v) {
#pragma unroll
  for (int o = 32; o > 0; o >>= 1) v = fmaxf(v, __shfl_down(v, o));
  return v;
}
DEV_INLINE float waveRedSum(float v) {
#pragma unroll
  for (int o = 32; o > 0; o >>= 1) v += __shfl_down(v, o);
  return v;
}

// ---------------- async global->LDS staging (linear LDS + swizzled source) ----------------
DEV_INLINE void gll16(const void* g, void* l) {
  __builtin_amdgcn_global_load_lds(
      reinterpret_cast<__attribute__((address_space(1))) void*>(
          reinterpret_cast<uintptr_t>(g)),
      reinterpret_cast<__attribute__((address_space(3))) void*>(
          reinterpret_cast<uintptr_t>(l)),
      16, 0, 0);
}

// Stage ROWS x (UPR*8) shorts; lda in shorts. Physical slot qp holds logical
// unit q = qp ^ (row & MASK); fragment reads apply the same XOR.
template <int ROWS, int UPR, int MASK>
DEV_INLINE void stageT(const unsigned short* __restrict__ g, int lda,
                       unsigned short* l) {
  int t = threadIdx.x, w = t >> 6, lane = t & 63;
  constexpr int NI = (ROWS * UPR) / 64;
  constexpr int PW = NI / 4;
#pragma unroll
  for (int j = 0; j < PW; ++j) {
    int u0 = (w * PW + j) * 64;
    int u = u0 + lane;
    int row = u / UPR, qp = u % UPR;
    int q = qp ^ (row & MASK);
    gll16(g + (size_t)row * lda + q * 8, l + (size_t)u0 * 8);
  }
}

template <int MASK>
DEV_INLINE short8 fragLd(const unsigned short* base, int row, int q, int rowShorts) {
  int qp = q ^ (row & MASK);
  return *(const short8*)(base + row * rowShorts + qp * 8);
}

// ================= stage 1 =================
__global__ void k_qs(const float* __restrict__ x, const float* __restrict__ Wq_s,
                     float* __restrict__ ws) {
  int c = blockIdx.x, t = threadIdx.x;
  __shared__ float xl[E_];
  xl[t] = x[(size_t)c * E_ + t];
  __syncthreads();
  float s = 0.f;
#pragma unroll 8
  for (int k = 0; k < E_; ++k) s += xl[k] * Wq_s[(size_t)k * E_ + t];
  ws[o_qs + (size_t)c * E_ + t] = s * 0.17677669529663687f;
}

// Pb[c][h][k] bf16, h padded to 16 with zeros
__global__ void k_p(const float* __restrict__ Wk_s, const float* __restrict__ ws,
                    unsigned short* __restrict__ Pb) {
  int h = blockIdx.x, c = blockIdx.y, t = threadIdx.x;
  __shared__ float q[D_];
  float s = 0.f;
  if (h < 12) {
    if (t < D_) q[t] = ws[o_qs + (size_t)c * E_ + h * D_ + t];
    __syncthreads();
    const float* wrow = &Wk_s[(size_t)t * E_ + h * D_];
#pragma unroll
    for (int d = 0; d < D_; d += 4) {
      float4 w = *(const float4*)&wrow[d];
      s += w.x * q[d] + w.y * q[d + 1] + w.z * q[d + 2] + w.w * q[d + 3];
    }
  }
  Pb[((size_t)c * 16 + h) * 384 + t] = bf16h(s);
}

// ---------------- fused logits + softmax_r -> swT[h][r][c] ----------------
__global__ __launch_bounds__(256) void k_logits_sm(
    const unsigned short* __restrict__ xb, const unsigned short* __restrict__ Pb,
    const int* __restrict__ seq_mask, float* __restrict__ swT) {
  int c = blockIdx.x, t = threadIdx.x;
  __shared__ unsigned short sA[256 * 32];  // 16KB
  __shared__ unsigned short sB[16 * 32];   // 1KB
  __shared__ float lg[12 * 256];           // 12KB
  __shared__ float red[4];
  int w = t >> 6, lane = t & 63, id16 = lane & 15, g = lane >> 4;
  f32x4 acc[4];
#pragma unroll
  for (int mi = 0; mi < 4; ++mi) acc[mi] = (f32x4){0.f, 0.f, 0.f, 0.f};

  for (int k0 = 0; k0 < 384; k0 += 32) {
    // A: 256 rows (r) x 4 octets; row stride in xb = 384*384 shorts
    stageT<256, 4, 3>(xb + (size_t)c * 384 + k0, 384 * 384, sA);
    // B: 16 rows (h) x 4 octets (one wave)
    if (w == 0) {
      int row = lane >> 2, qp = lane & 3, q = qp ^ (row & 3);
      gll16(Pb + ((size_t)c * 16 + row) * 384 + k0 + q * 8, sB);
    }
    __syncthreads();
    short8 Bf = fragLd<3>(sB, id16, g, 32);
#pragma unroll
    for (int mi = 0; mi < 4; ++mi) {
      short8 Af = fragLd<3>(sA, w * 64 + mi * 16 + id16, g, 32);
      acc[mi] = __builtin_amdgcn_mfma_f32_16x16x32_bf16(Af, Bf, acc[mi], 0, 0, 0);
    }
    __syncthreads();
  }
  int l4 = (lane >> 4) * 4;
#pragma unroll
  for (int mi = 0; mi < 4; ++mi) {
    if (id16 < 12) {
      f32x4 a = acc[mi];
#pragma unroll
      for (int reg = 0; reg < 4; ++reg)
        lg[id16 * 256 + w * 64 + mi * 16 + l4 + reg] = a[reg];
    }
  }
  __syncthreads();
  // softmax over r (t = r), per h
  int wid = t >> 6;
  const float scal = 0.17677669529663687f / sqrtf((float)C_);
  bool masked = (seq_mask[t] == 0);
  for (int h = 0; h < 12; ++h) {
    float v = masked ? NEGF : lg[h * 256 + t];
    float m = waveRedMax(v);
    if ((t & 63) == 0) red[wid] = m;
    __syncthreads();
    float mx = fmaxf(fmaxf(red[0], red[1]), fmaxf(red[2], red[3]));
    __syncthreads();
    float e = expf(v - mx);
    float s = waveRedSum(e);
    if ((t & 63) == 0) red[wid] = s;
    __syncthreads();
    float sum = red[0] + red[1] + red[2] + red[3];
    swT[((size_t)h * 256 + t) * 384 + c] = e / sum * scal;
    __syncthreads();
  }
}

// ---------------- conversions ----------------
__global__ void k_cvt_x(const float* __restrict__ x, unsigned short* __restrict__ xb) {
  size_t i = ((size_t)blockIdx.x * 256 + threadIdx.x) * 16;
  unsigned short h[16];
#pragma unroll
  for (int j = 0; j < 4; ++j) {
    float4 f = *(const float4*)&x[i + j * 4];
    h[j * 4 + 0] = bf16h(f.x);
    h[j * 4 + 1] = bf16h(f.y);
    h[j * 4 + 2] = bf16h(f.z);
    h[j * 4 + 3] = bf16h(f.w);
  }
  *(short8*)&xb[i] = *(const short8*)&h[0];
  *(short8*)&xb[i + 8] = *(const short8*)&h[8];
}

__global__ void k_cvt_w(const float* __restrict__ Wq, const float* __restrict__ Wk,
                        const float* __restrict__ Wv, unsigned short* __restrict__ Wtb) {
  int n = blockIdx.x, k = threadIdx.x;
  const float* W;
  int col;
  if (n < 384)      { W = Wq; col = n; }
  else if (n < 768) { W = Wk; col = n - 384; }
  else              { W = Wv; col = n - 768; }
  Wtb[(size_t)n * 384 + k] = bf16h(W[(size_t)k * 384 + col]);
}

// ---------------- k_proj_all: 128x128 tile, BK=64, single-buffer gll ----------------
__global__ __launch_bounds__(256, 4) void k_proj_all(
    const unsigned short* __restrict__ xb, const unsigned short* __restrict__ Wtb,
    const float* __restrict__ swT, unsigned short* __restrict__ Q3b,
    unsigned short* __restrict__ K3b, unsigned short* __restrict__ V3b) {
  __shared__ unsigned short sA[128 * 64], sB[128 * 64];  // 32KB
  int Dd = blockIdx.x;                       // 6912 blocks; /8 = 864 -> bijective
  int L = (Dd & 7) * 864 + (Dd >> 3);
  int bm = L / 9, bn = L - bm * 9;
  int n0 = bn * 128, m0 = bm * 128;
  int wave = threadIdx.x >> 6, wr = wave >> 1, wc = wave & 1;
  int lane = threadIdx.x & 63, id16 = lane & 15, g = lane >> 4;
  f32x4 acc[4][4];
#pragma unroll
  for (int mi = 0; mi < 4; ++mi)
#pragma unroll
    for (int ni = 0; ni < 4; ++ni) acc[mi][ni] = (f32x4){0.f, 0.f, 0.f, 0.f};

  for (int it = 0; it < 6; ++it) {
    stageT<128, 8, 7>(xb + (size_t)m0 * 384 + it * 64, 384, sA);
    stageT<128, 8, 7>(Wtb + (size_t)n0 * 384 + it * 64, 384, sB);
    __syncthreads();
    short8 Af[4][2], Bf[4][2];
#pragma unroll
    for (int mi = 0; mi < 4; ++mi) {
      int row = wr * 64 + mi * 16 + id16;
#pragma unroll
      for (int kk = 0; kk < 2; ++kk) Af[mi][kk] = fragLd<7>(sA, row, kk * 4 + g, 64);
    }
#pragma unroll
    for (int ni = 0; ni < 4; ++ni) {
      int col = wc * 64 + ni * 16 + id16;
#pragma unroll
      for (int kk = 0; kk < 2; ++kk) Bf[ni][kk] = fragLd<7>(sB, col, kk * 4 + g, 64);
    }
#pragma unroll
    for (int kk = 0; kk < 2; ++kk)
#pragma unroll
      for (int mi = 0; mi < 4; ++mi)
#pragma unroll
        for (int ni = 0; ni < 4; ++ni)
          acc[mi][ni] = __builtin_amdgcn_mfma_f32_16x16x32_bf16(Af[mi][kk], Bf[ni][kk],
                                                                acc[mi][ni], 0, 0, 0);
    __syncthreads();
  }

  int l4 = (lane >> 4) * 4;
  int r = bm / 3, cb = (bm % 3) * 128;  // r constant per tile (384 = 3*128)
  if (bn < 6) {
#pragma unroll
    for (int mi = 0; mi < 4; ++mi) {
      int cbase = cb + wr * 64 + mi * 16 + l4;
#pragma unroll
      for (int ni = 0; ni < 4; ++ni) {
        int n = n0 + wc * 64 + ni * 16 + id16;
        bool isQ = n < 384;
        int nn = isQ ? n : n - 384;
        int hh = nn >> 5, dd = nn & 31;
        f32x4 a = acc[mi][ni];
        if (isQ) {
          float4 sv = *(const float4*)&swT[((size_t)hh * 256 + r) * 384 + cbase];
          a[0] *= sv.x; a[1] *= sv.y; a[2] *= sv.z; a[3] *= sv.w;
        }
        unsigned short* dst = isQ ? Q3b : K3b;
#pragma unroll
        for (int reg = 0; reg < 4; ++reg)
          dst[((size_t)(hh * 384 + cbase + reg)) * 8192 + r * 32 + dd] = bf16h(a[reg]);
      }
    }
  } else {  // V: V3b[h][r*32+d][c]
#pragma unroll
    for (int mi = 0; mi < 4; ++mi) {
      int c0 = cb + wr * 64 + mi * 16 + l4;
#pragma unroll
      for (int ni = 0; ni < 4; ++ni) {
        int nv = n0 + wc * 64 + ni * 16 + id16 - 768;
        int hh = nv >> 5, dd = nv & 31;
        f32x4 a = acc[mi][ni];
        u16x4 hv;
#pragma unroll
        for (int reg = 0; reg < 4; ++reg) hv[reg] = bf16h(a[reg]);
        *(u16x4*)(V3b + ((size_t)hh * 8192 + r * 32 + dd) * 384 + c0) = hv;
      }
    }
  }
}

// ---------------- k_qk_mma: 64x64 tile, BK=128, split-K x2, single-buffer ----------------
__global__ __launch_bounds__(256, 4) void k_qk_mma(
    const unsigned short* __restrict__ Q3b, const unsigned short* __restrict__ K3b,
    float* __restrict__ QKf0, float* __restrict__ QKf1) {
  __shared__ unsigned short sA[64 * 128], sB[64 * 128];  // 32KB
  int Dd = blockIdx.x;                       // 864 blocks; /8 = 108 -> bijective
  int L = (Dd & 7) * 108 + (Dd >> 3);
  int kh = L / 432, rem = L - kh * 432;
  int h = rem / 36, r2 = rem - h * 36, bi = r2 / 6, bj = r2 - bi * 6;
  int wave = threadIdx.x >> 6, wr = wave >> 1, wc = wave & 1;
  int lane = threadIdx.x & 63, id16 = lane & 15, g = lane >> 4;
  f32x4 acc[2][2];
#pragma unroll
  for (int mi = 0; mi < 2; ++mi)
#pragma unroll
    for (int ni = 0; ni < 2; ++ni) acc[mi][ni] = (f32x4){0.f, 0.f, 0.f, 0.f};
  const unsigned short* Ab =
      Q3b + (size_t)h * 384 * 8192 + (size_t)(bi * 64) * 8192 + kh * 4096;
  const unsigned short* Bb =
      K3b + (size_t)h * 384 * 8192 + (size_t)(bj * 64) * 8192 + kh * 4096;

  for (int it = 0; it < 32; ++it) {
    stageT<64, 16, 7>(Ab + it * 128, 8192, sA);
    stageT<64, 16, 7>(Bb + it * 128, 8192, sB);
    __syncthreads();
    short8 Af[2][4], Bf[2][4];
#pragma unroll
    for (int mi = 0; mi < 2; ++mi) {
      int row = wr * 32 + mi * 16 + id16;
#pragma unroll
      for (int kk = 0; kk < 4; ++kk) Af[mi][kk] = fragLd<7>(sA, row, kk * 4 + g, 128);
    }
#pragma unroll
    for (int ni = 0; ni < 2; ++ni) {
      int col = wc * 32 + ni * 16 + id16;
#pragma unroll
      for (int kk = 0; kk < 4; ++kk) Bf[ni][kk] = fragLd<7>(sB, col, kk * 4 + g, 128);
    }
#pragma unroll
    for (int kk = 0; kk < 4; ++kk)
#pragma unroll
      for (int mi = 0; mi < 2; ++mi)
#pragma unroll
        for (int ni = 0; ni < 2; ++ni)
          acc[mi][ni] = __builtin_amdgcn_mfma_f32_16x16x32_bf16(Af[mi][kk], Bf[ni][kk],
                                                                acc[mi][ni], 0, 0, 0);
    __syncthreads();
  }
  int l4 = (lane >> 4) * 4;
  float* dst = kh ? QKf1 : QKf0;
#pragma unroll
  for (int mi = 0; mi < 2; ++mi)
#pragma unroll
    for (int ni = 0; ni < 2; ++ni) {
      int i0 = bi * 64 + wr * 32 + mi * 16 + l4;
      int j = bj * 64 + wc * 32 + ni * 16 + id16;
      f32x4 a = acc[mi][ni];
#pragma unroll
      for (int reg = 0; reg < 4; ++reg)
        dst[((size_t)h * 384 + i0 + reg) * 384 + j] = a[reg];
    }
}

// ---------------- k_softmax_j: sum split-K, softmax, emit bf16 only ----------------
__global__ void k_softmax_j(const int* __restrict__ res_mask, const float* __restrict__ QKf0,
                            const float* __restrict__ QKf1,
                            unsigned short* __restrict__ attnb) {
  int i = blockIdx.x, h = blockIdx.y, t = threadIdx.x;
  int lane = t & 63, wid = t >> 6;
  size_t base = ((size_t)h * C_ + i) * C_;
  float v = QKf0[base + t] + QKf1[base + t];
  if ((res_mask[i] * res_mask[t]) == 0) v = NEGF;
  __shared__ float red[6];
  float m = waveRedMax(v);
  if (lane == 0) red[wid] = m;
  __syncthreads();
  float mx = red[0];
#pragma unroll
  for (int w = 1; w < 6; ++w) mx = fmaxf(mx, red[w]);
  __syncthreads();
  float e = expf(v - mx);
  float s = waveRedSum(e);
  if (lane == 0) red[wid] = s;
  __syncthreads();
  float sum = 0.f;
#pragma unroll
  for (int w = 0; w < 6; ++w) sum += red[w];
  attnb[base + t] = bf16h(e / sum);
}

// ---------------- k_out_mma: 128x128 tile, BK=64, single-buffer ----------------
__global__ __launch_bounds__(256, 4) void k_out_mma(
    const unsigned short* __restrict__ attnb, const unsigned short* __restrict__ V3b,
    float* __restrict__ out) {
  __shared__ unsigned short sA[128 * 64], sB[128 * 64];
  int Dd = blockIdx.x;                        // 2304 blocks; /8 = 288 -> bijective
  int L = (Dd & 7) * 288 + (Dd >> 3);
  int bn = L % 64, bm = (L / 64) % 3, h = L / 192;
  int n0 = bn * 128, m0 = bm * 128;
  int wave = threadIdx.x >> 6, wr = wave >> 1, wc = wave & 1;
  int lane = threadIdx.x & 63, id16 = lane & 15, g = lane >> 4;
  f32x4 acc[4][4];
#pragma unroll
  for (int mi = 0; mi < 4; ++mi)
#pragma unroll
    for (int ni = 0; ni < 4; ++ni) acc[mi][ni] = (f32x4){0.f, 0.f, 0.f, 0.f};
  const unsigned short* Ab = attnb + (size_t)h * 384 * 384 + (size_t)m0 * 384;
  const unsigned short* Bb = V3b + (size_t)h * 8192 * 384 + (size_t)n0 * 384;

  for (int it = 0; it < 6; ++it) {
    stageT<128, 8, 7>(Ab + it * 64, 384, sA);
    stageT<128, 8, 7>(Bb + it * 64, 384, sB);
    __syncthreads();
    short8 Af[4][2], Bf[4][2];
#pragma unroll
    for (int mi = 0; mi < 4; ++mi) {
      int row = wr * 64 + mi * 16 + id16;
#pragma unroll
      for (int kk = 0; kk < 2; ++kk) Af[mi][kk] = fragLd<7>(sA, row, kk * 4 + g, 64);
    }
#pragma unroll
    for (int ni = 0; ni < 4; ++ni) {
      int col = wc * 64 + ni * 16 + id16;
#pragma unroll
      for (int kk = 0; kk < 2; ++kk) Bf[ni][kk] = fragLd<7>(sB, col, kk * 4 + g, 64);
    }
#pragma unroll
    for (int kk = 0; kk < 2; ++kk)
#pragma unroll
      for (int mi = 0; mi < 4; ++mi)
#pragma unroll
        for (int ni = 0; ni < 4; ++ni)
          acc[mi][ni] = __builtin_amdgcn_mfma_f32_16x16x32_bf16(Af[mi][kk], Bf[ni][kk],
                                                                acc[mi][ni], 0, 0, 0);
    __syncthreads();
  }
  int l4 = (lane >> 4) * 4;
#pragma unroll
  for (int mi = 0; mi < 4; ++mi)
#pragma unroll
    for (int ni = 0; ni < 4; ++ni) {
      int i0 = m0 + wr * 64 + mi * 16 + l4;
      int n = n0 + wc * 64 + ni * 16 + id16;  // rd index
      int r = n >> 5, d = n & 31;
      f32x4 a = acc[mi][ni];
#pragma unroll
      for (int reg = 0; reg < 4; ++reg)
        out[(((size_t)r * 384 + i0 + reg) * 12 + h) * 32 + d] = a[reg];
    }
}

extern "C" void kernel_launch(void* const* d_in, const int* in_sizes, int n_in,
                              void* d_out, int out_size, void* d_ws, size_t ws_size,
                              hipStream_t stream) {
  const float* x = (const float*)d_in[0];
  const float* Wq = (const float*)d_in[1];
  const float* Wk = (const float*)d_in[2];
  const float* Wv = (const float*)d_in[3];
  const float* Wq_s = (const float*)d_in[4];
  const float* Wk_s = (const float*)d_in[5];
  const int* res_mask = (const int*)d_in[6];
  const int* seq_mask = (const int*)d_in[7];
  float* ws = (float*)d_ws;
  char* wsb = (char*)d_ws;
  float* out = (float*)d_out;

  unsigned short* Pb  = (unsigned short*)(wsb + o_p * 4);
  float* swT          = ws + o_logits;
  unsigned short* Wtb = (unsigned short*)(wsb + o_attn * 4);  // dead before qk writes QKf0
  float* QKf0         = ws + o_attn;
  unsigned short* Q3b = (unsigned short*)(wsb + ob_q3b);
  unsigned short* K3b = (unsigned short*)(wsb + ob_k3b);
  unsigned short* V3b = (unsigned short*)(wsb + ob_v3b);
  unsigned short* xb  = (unsigned short*)(wsb + ob_xb);
  unsigned short* attnb = Q3b;              // overlays Q3b (dead after qk)
  float* QKf1 = (float*)(wsb + ob_xb);      // overlays xb (dead after proj)

  hipLaunchKernelGGL(k_cvt_x, dim3(9216), dim3(256), 0, stream, x, xb);
  hipLaunchKernelGGL(k_qs, dim3(C_), dim3(E_), 0, stream, x, Wq_s, ws);
  hipLaunchKernelGGL(k_p, dim3(16, C_), dim3(E_), 0, stream, Wk_s, ws, Pb);
  hipLaunchKernelGGL(k_logits_sm, dim3(C_), dim3(256), 0, stream, xb, Pb, seq_mask, swT);
  hipLaunchKernelGGL(k_cvt_w, dim3(1152), dim3(384), 0, stream, Wq, Wk, Wv, Wtb);
  hipLaunchKernelGGL(k_proj_all, dim3(6912), dim3(256), 0, stream, xb, Wtb, swT,
                     Q3b, K3b, V3b);
  hipLaunchKernelGGL(k_qk_mma, dim3(864), dim3(256), 0, stream, Q3b, K3b, QKf0, QKf1);
  hipLaunchKernelGGL(k_softmax_j, dim3(C_, H_), dim3(C_), 0, stream, res_mask,
                     QKf0, QKf1, attnb);
  hipLaunchKernelGGL(k_out_mma, dim3(2304), dim3(256), 0, stream, attnb, V3b, out);
}

// Round 14
// 399.531 us; speedup vs baseline: 6.6936x; 1.0308x over previous
//
#include <hip/hip_runtime.h>
#include <math.h>
#include <stdint.h>

#define DEV_INLINE __device__ __forceinline__

constexpr int R_ = 256, C_ = 384, E_ = 384, H_ = 12, D_ = 32;
constexpr float NEGF = -3.402823466e38f;

typedef __attribute__((ext_vector_type(4))) float f32x4;
typedef __attribute__((ext_vector_type(8))) short short8;
typedef __attribute__((ext_vector_type(4))) unsigned short u16x4;

// ---------------- workspace layout ----------------
constexpr size_t o_qs     = 0;                                 // C*E f32 (qs)
constexpr size_t o_p      = o_qs + (size_t)C_ * E_;            // Pb bf16 overlay
constexpr size_t o_logits = o_p + (size_t)C_ * H_ * E_;        // swT f32 [12][256][384]
constexpr size_t o_sw     = o_logits + (size_t)C_ * H_ * R_;   // (free)
constexpr size_t o_attn   = o_sw + (size_t)C_ * H_ * R_;       // QKf0; Wtb overlays pre-qk
constexpr size_t o_q3     = o_attn + (size_t)H_ * C_ * C_;
constexpr size_t SZBIG  = 75497472;                  // bytes per big region
constexpr size_t ob_q3b = o_q3 * 4;                  // 24,182,784 (attnb overlays after qk)
constexpr size_t ob_k3b = ob_q3b + SZBIG;
constexpr size_t ob_v3b = ob_k3b + SZBIG;
constexpr size_t ob_xb  = ob_v3b + SZBIG;            // ends 326,172,672

// ---------------- helpers ----------------
DEV_INLINE unsigned short bf16h(float x) {
  unsigned int u = __builtin_bit_cast(unsigned int, x);
  unsigned int r = (u + 0x7FFFu + ((u >> 16) & 1u)) >> 16;
  return (unsigned short)r;
}
DEV_INLINE float waveRedMax(float v) {
#pragma unroll
  for (int o = 32; o > 0; o >>= 1) v = fmaxf(v, __shfl_down(v, o));
  return v;
}
DEV_INLINE float waveRedSum(float v) {
#pragma unroll
  for (int o = 32; o > 0; o >>= 1) v += __shfl_down(v, o);
  return v;
}

// ---------------- async global->LDS staging (linear LDS + swizzled source) ----------------
DEV_INLINE void gll16(const void* g, void* l) {
  __builtin_amdgcn_global_load_lds(
      reinterpret_cast<__attribute__((address_space(1))) void*>(
          reinterpret_cast<uintptr_t>(g)),
      reinterpret_cast<__attribute__((address_space(3))) void*>(
          reinterpret_cast<uintptr_t>(l)),
      16, 0, 0);
}

// Stage ROWS x (UPR*8) shorts; lda in shorts. Physical slot qp holds logical
// unit q = qp ^ ((row>>SHIFT) & MASK); fragment reads apply the same XOR.
template <int ROWS, int UPR, int MASK, int SHIFT>
DEV_INLINE void stageT(const unsigned short* __restrict__ g, int lda,
                       unsigned short* l) {
  int t = threadIdx.x, w = t >> 6, lane = t & 63;
  constexpr int NI = (ROWS * UPR) / 64;
  constexpr int PW = NI / 4;
#pragma unroll
  for (int j = 0; j < PW; ++j) {
    int u0 = (w * PW + j) * 64;
    int u = u0 + lane;
    int row = u / UPR, qp = u % UPR;
    int q = qp ^ ((row >> SHIFT) & MASK);
    gll16(g + (size_t)row * lda + q * 8, l + (size_t)u0 * 8);
  }
}

template <int MASK, int SHIFT>
DEV_INLINE short8 fragLd(const unsigned short* base, int row, int q, int rowShorts) {
  int qp = q ^ ((row >> SHIFT) & MASK);
  return *(const short8*)(base + row * rowShorts + qp * 8);
}

// ================= stage 1 =================
__global__ void k_qs(const float* __restrict__ x, const float* __restrict__ Wq_s,
                     float* __restrict__ ws) {
  int c = blockIdx.x, t = threadIdx.x;
  __shared__ float xl[E_];
  xl[t] = x[(size_t)c * E_ + t];
  __syncthreads();
  float s = 0.f;
#pragma unroll 8
  for (int k = 0; k < E_; ++k) s += xl[k] * Wq_s[(size_t)k * E_ + t];
  ws[o_qs + (size_t)c * E_ + t] = s * 0.17677669529663687f;
}

__global__ void k_p(const float* __restrict__ Wk_s, const float* __restrict__ ws,
                    unsigned short* __restrict__ Pb) {
  int h = blockIdx.x, c = blockIdx.y, t = threadIdx.x;
  __shared__ float q[D_];
  float s = 0.f;
  if (h < 12) {
    if (t < D_) q[t] = ws[o_qs + (size_t)c * E_ + h * D_ + t];
    __syncthreads();
    const float* wrow = &Wk_s[(size_t)t * E_ + h * D_];
#pragma unroll
    for (int d = 0; d < D_; d += 4) {
      float4 w = *(const float4*)&wrow[d];
      s += w.x * q[d] + w.y * q[d + 1] + w.z * q[d + 2] + w.w * q[d + 3];
    }
  }
  Pb[((size_t)c * 16 + h) * 384 + t] = bf16h(s);
}

// ---------------- fused logits + softmax_r -> swT[h][r][c] ----------------
__global__ __launch_bounds__(256) void k_logits_sm(
    const unsigned short* __restrict__ xb, const unsigned short* __restrict__ Pb,
    const int* __restrict__ seq_mask, float* __restrict__ swT) {
  int c = blockIdx.x, t = threadIdx.x;
  __shared__ unsigned short sA[256 * 32];
  __shared__ unsigned short sB[16 * 32];
  __shared__ float lg[12 * 256];
  __shared__ float red[4];
  int w = t >> 6, lane = t & 63, id16 = lane & 15, g = lane >> 4;
  f32x4 acc[4];
#pragma unroll
  for (int mi = 0; mi < 4; ++mi) acc[mi] = (f32x4){0.f, 0.f, 0.f, 0.f};

  for (int k0 = 0; k0 < 384; k0 += 32) {
    stageT<256, 4, 3, 0>(xb + (size_t)c * 384 + k0, 384 * 384, sA);
    if (w == 0) {
      int row = lane >> 2, qp = lane & 3, q = qp ^ (row & 3);
      gll16(Pb + ((size_t)c * 16 + row) * 384 + k0 + q * 8, sB);
    }
    __syncthreads();
    short8 Bf = fragLd<3, 0>(sB, id16, g, 32);
#pragma unroll
    for (int mi = 0; mi < 4; ++mi) {
      short8 Af = fragLd<3, 0>(sA, w * 64 + mi * 16 + id16, g, 32);
      acc[mi] = __builtin_amdgcn_mfma_f32_16x16x32_bf16(Af, Bf, acc[mi], 0, 0, 0);
    }
    __syncthreads();
  }
  int l4 = (lane >> 4) * 4;
#pragma unroll
  for (int mi = 0; mi < 4; ++mi) {
    if (id16 < 12) {
      f32x4 a = acc[mi];
#pragma unroll
      for (int reg = 0; reg < 4; ++reg)
        lg[id16 * 256 + w * 64 + mi * 16 + l4 + reg] = a[reg];
    }
  }
  __syncthreads();
  int wid = t >> 6;
  const float scal = 0.17677669529663687f / sqrtf((float)C_);
  bool masked = (seq_mask[t] == 0);
  for (int h = 0; h < 12; ++h) {
    float v = masked ? NEGF : lg[h * 256 + t];
    float m = waveRedMax(v);
    if ((t & 63) == 0) red[wid] = m;
    __syncthreads();
    float mx = fmaxf(fmaxf(red[0], red[1]), fmaxf(red[2], red[3]));
    __syncthreads();
    float e = expf(v - mx);
    float s = waveRedSum(e);
    if ((t & 63) == 0) red[wid] = s;
    __syncthreads();
    float sum = red[0] + red[1] + red[2] + red[3];
    swT[((size_t)h * 256 + t) * 384 + c] = e / sum * scal;
    __syncthreads();
  }
}

// ---------------- conversions ----------------
__global__ void k_cvt_x(const float* __restrict__ x, unsigned short* __restrict__ xb) {
  size_t i = ((size_t)blockIdx.x * 256 + threadIdx.x) * 16;
  unsigned short h[16];
#pragma unroll
  for (int j = 0; j < 4; ++j) {
    float4 f = *(const float4*)&x[i + j * 4];
    h[j * 4 + 0] = bf16h(f.x);
    h[j * 4 + 1] = bf16h(f.y);
    h[j * 4 + 2] = bf16h(f.z);
    h[j * 4 + 3] = bf16h(f.w);
  }
  *(short8*)&xb[i] = *(const short8*)&h[0];
  *(short8*)&xb[i + 8] = *(const short8*)&h[8];
}

__global__ void k_cvt_w(const float* __restrict__ Wq, const float* __restrict__ Wk,
                        const float* __restrict__ Wv, unsigned short* __restrict__ Wtb) {
  int n = blockIdx.x, k = threadIdx.x;
  const float* W;
  int col;
  if (n < 384)      { W = Wq; col = n; }
  else if (n < 768) { W = Wk; col = n - 384; }
  else              { W = Wv; col = n - 768; }
  Wtb[(size_t)n * 384 + k] = bf16h(W[(size_t)k * 384 + col]);
}

// ---------------- k_proj_all: 128x128 tile, BK=64, LDS-transpose epilogue ----------------
// Q3b/K3b layout: [h][r][c*32+d]; V3b layout: [h][r*32+d][c]
__global__ __launch_bounds__(256, 4) void k_proj_all(
    const unsigned short* __restrict__ xb, const unsigned short* __restrict__ Wtb,
    const float* __restrict__ swT, unsigned short* __restrict__ Q3b,
    unsigned short* __restrict__ K3b, unsigned short* __restrict__ V3b) {
  __shared__ unsigned short smem[2 * 128 * 64];  // 32KB: sA|sB, reused by epilogue
  unsigned short* sA = smem;
  unsigned short* sB = smem + 128 * 64;
  int Dd = blockIdx.x;                       // 6912 blocks; /8 = 864 -> bijective
  int L = (Dd & 7) * 864 + (Dd >> 3);
  int bm = L / 9, bn = L - bm * 9;
  int n0 = bn * 128, m0 = bm * 128;
  int wave = threadIdx.x >> 6, wr = wave >> 1, wc = wave & 1;
  int lane = threadIdx.x & 63, id16 = lane & 15, g = lane >> 4;
  f32x4 acc[4][4];
#pragma unroll
  for (int mi = 0; mi < 4; ++mi)
#pragma unroll
    for (int ni = 0; ni < 4; ++ni) acc[mi][ni] = (f32x4){0.f, 0.f, 0.f, 0.f};

  for (int it = 0; it < 6; ++it) {
    stageT<128, 8, 7, 0>(xb + (size_t)m0 * 384 + it * 64, 384, sA);
    stageT<128, 8, 7, 0>(Wtb + (size_t)n0 * 384 + it * 64, 384, sB);
    __syncthreads();
    short8 Af[4][2], Bf[4][2];
#pragma unroll
    for (int mi = 0; mi < 4; ++mi) {
      int row = wr * 64 + mi * 16 + id16;
#pragma unroll
      for (int kk = 0; kk < 2; ++kk) Af[mi][kk] = fragLd<7, 0>(sA, row, kk * 4 + g, 64);
    }
#pragma unroll
    for (int ni = 0; ni < 4; ++ni) {
      int col = wc * 64 + ni * 16 + id16;
#pragma unroll
      for (int kk = 0; kk < 2; ++kk) Bf[ni][kk] = fragLd<7, 0>(sB, col, kk * 4 + g, 64);
    }
#pragma unroll
    for (int kk = 0; kk < 2; ++kk)
#pragma unroll
      for (int mi = 0; mi < 4; ++mi)
#pragma unroll
        for (int ni = 0; ni < 4; ++ni)
          acc[mi][ni] = __builtin_amdgcn_mfma_f32_16x16x32_bf16(Af[mi][kk], Bf[ni][kk],
                                                                acc[mi][ni], 0, 0, 0);
    __syncthreads();  // also guards smem reuse by epilogue
  }

  int l4 = (lane >> 4) * 4;
  int r = bm / 3, cb = (bm % 3) * 128;  // r constant per tile (384 = 3*128)
  if (bn < 6) {
    // Q (bn<3) or K: stage [hhl 4][c 128][d 32] bf16 into smem, then copy out
    bool isQ = bn < 3;
    int hbase = isQ ? bn * 4 : (bn - 3) * 4;
#pragma unroll
    for (int mi = 0; mi < 4; ++mi) {
      int clBase = wr * 64 + mi * 16 + l4;
#pragma unroll
      for (int ni = 0; ni < 4; ++ni) {
        int nl = wc * 64 + ni * 16 + id16;
        int hhl = nl >> 5, d = nl & 31;
        f32x4 a = acc[mi][ni];
        if (isQ) {
          float4 sv =
              *(const float4*)&swT[((size_t)(hbase + hhl) * 256 + r) * 384 + cb + clBase];
          a[0] *= sv.x; a[1] *= sv.y; a[2] *= sv.z; a[3] *= sv.w;
        }
#pragma unroll
        for (int reg = 0; reg < 4; ++reg)
          smem[hhl * 4096 + (clBase + reg) * 32 + d] = bf16h(a[reg]);
      }
    }
    __syncthreads();
    unsigned short* dst = isQ ? Q3b : K3b;
#pragma unroll
    for (int seg = 0; seg < 8; ++seg) {
      int off = seg * 2048 + threadIdx.x * 8;
      int hhl = off >> 12, inner = off & 4095;
      int hg = hbase + hhl;
      *(short8*)(dst + (((size_t)hg * 256 + r) * 384 + cb) * 32 + inner) =
          *(const short8*)(smem + off);
    }
  } else {  // V: direct write (R13-verified path), V3b[h][r*32+d][c]
    int r2 = r, cb2 = cb;
#pragma unroll
    for (int mi = 0; mi < 4; ++mi) {
      int c0 = cb2 + wr * 64 + mi * 16 + l4;
#pragma unroll
      for (int ni = 0; ni < 4; ++ni) {
        int nv = n0 + wc * 64 + ni * 16 + id16 - 768;
        int hh = nv >> 5, dd = nv & 31;
        f32x4 a = acc[mi][ni];
        u16x4 hv;
#pragma unroll
        for (int reg = 0; reg < 4; ++reg) hv[reg] = bf16h(a[reg]);
        *(u16x4*)(V3b + ((size_t)hh * 8192 + r2 * 32 + dd) * 384 + c0) = hv;
      }
    }
  }
}

// ---------------- k_qk_mma: 128x128 tiles, K over (r,d), split-K x2 ----------------
__global__ __launch_bounds__(256, 4) void k_qk_mma(
    const unsigned short* __restrict__ Q3b, const unsigned short* __restrict__ K3b,
    float* __restrict__ QKf0, float* __restrict__ QKf1) {
  __shared__ unsigned short sA[2 * 4096], sB[2 * 4096];  // 16KB each
  int Dd = blockIdx.x;                       // 216 blocks; /8 = 27 -> bijective
  int L = (Dd & 7) * 27 + (Dd >> 3);
  int kh = L / 108, rem = L - kh * 108;
  int h = rem / 9, r2 = rem - h * 9, bi = r2 / 3, bj = r2 - bi * 3;
  int i0 = bi * 128, j0 = bj * 128;
  int wave = threadIdx.x >> 6, wr = wave >> 1, wc = wave & 1;
  int lane = threadIdx.x & 63, id16 = lane & 15, g = lane >> 4;
  f32x4 acc[4][4];
#pragma unroll
  for (int mi = 0; mi < 4; ++mi)
#pragma unroll
    for (int ni = 0; ni < 4; ++ni) acc[mi][ni] = (f32x4){0.f, 0.f, 0.f, 0.f};

  for (int it = 0; it < 64; ++it) {
    int r = kh * 128 + it * 2;
#pragma unroll
    for (int rr = 0; rr < 2; ++rr) {
      stageT<128, 4, 3, 1>(Q3b + (((size_t)h * 256 + r + rr) * 384 + i0) * 32, 32,
                           sA + rr * 4096);
      stageT<128, 4, 3, 1>(K3b + (((size_t)h * 256 + r + rr) * 384 + j0) * 32, 32,
                           sB + rr * 4096);
    }
    __syncthreads();
#pragma unroll
    for (int rr = 0; rr < 2; ++rr) {
      short8 Af[4], Bf[4];
#pragma unroll
      for (int mi = 0; mi < 4; ++mi)
        Af[mi] = fragLd<3, 1>(sA + rr * 4096, wr * 64 + mi * 16 + id16, g, 32);
#pragma unroll
      for (int ni = 0; ni < 4; ++ni)
        Bf[ni] = fragLd<3, 1>(sB + rr * 4096, wc * 64 + ni * 16 + id16, g, 32);
#pragma unroll
      for (int mi = 0; mi < 4; ++mi)
#pragma unroll
        for (int ni = 0; ni < 4; ++ni)
          acc[mi][ni] = __builtin_amdgcn_mfma_f32_16x16x32_bf16(Af[mi], Bf[ni],
                                                                acc[mi][ni], 0, 0, 0);
    }
    __syncthreads();
  }
  int l4 = (lane >> 4) * 4;
  float* dst = kh ? QKf1 : QKf0;
#pragma unroll
  for (int mi = 0; mi < 4; ++mi)
#pragma unroll
    for (int ni = 0; ni < 4; ++ni) {
      int ii = i0 + wr * 64 + mi * 16 + l4;
      int j = j0 + wc * 64 + ni * 16 + id16;
      f32x4 a = acc[mi][ni];
#pragma unroll
      for (int reg = 0; reg < 4; ++reg)
        dst[((size_t)h * 384 + ii + reg) * 384 + j] = a[reg];
    }
}

// ---------------- k_softmax_j: sum split-K, softmax, emit bf16 ----------------
__global__ void k_softmax_j(const int* __restrict__ res_mask, const float* __restrict__ QKf0,
                            const float* __restrict__ QKf1,
                            unsigned short* __restrict__ attnb) {
  int i = blockIdx.x, h = blockIdx.y, t = threadIdx.x;
  int lane = t & 63, wid = t >> 6;
  size_t base = ((size_t)h * C_ + i) * C_;
  float v = QKf0[base + t] + QKf1[base + t];
  if ((res_mask[i] * res_mask[t]) == 0) v = NEGF;
  __shared__ float red[6];
  float m = waveRedMax(v);
  if (lane == 0) red[wid] = m;
  __syncthreads();
  float mx = red[0];
#pragma unroll
  for (int w = 1; w < 6; ++w) mx = fmaxf(mx, red[w]);
  __syncthreads();
  float e = expf(v - mx);
  float s = waveRedSum(e);
  if (lane == 0) red[wid] = s;
  __syncthreads();
  float sum = 0.f;
#pragma unroll
  for (int w = 0; w < 6; ++w) sum += red[w];
  attnb[base + t] = bf16h(e / sum);
}

// ---------------- k_out_mma: 128x128 tile, BK=64 (R13-verified) ----------------
__global__ __launch_bounds__(256, 4) void k_out_mma(
    const unsigned short* __restrict__ attnb, const unsigned short* __restrict__ V3b,
    float* __restrict__ out) {
  __shared__ unsigned short sA[128 * 64], sB[128 * 64];
  int Dd = blockIdx.x;                        // 2304 blocks; /8 = 288 -> bijective
  int L = (Dd & 7) * 288 + (Dd >> 3);
  int bn = L % 64, bm = (L / 64) % 3, h = L / 192;
  int n0 = bn * 128, m0 = bm * 128;
  int wave = threadIdx.x >> 6, wr = wave >> 1, wc = wave & 1;
  int lane = threadIdx.x & 63, id16 = lane & 15, g = lane >> 4;
  f32x4 acc[4][4];
#pragma unroll
  for (int mi = 0; mi < 4; ++mi)
#pragma unroll
    for (int ni = 0; ni < 4; ++ni) acc[mi][ni] = (f32x4){0.f, 0.f, 0.f, 0.f};
  const unsigned short* Ab = attnb + (size_t)h * 384 * 384 + (size_t)m0 * 384;
  const unsigned short* Bb = V3b + (size_t)h * 8192 * 384 + (size_t)n0 * 384;

  for (int it = 0; it < 6; ++it) {
    stageT<128, 8, 7, 0>(Ab + it * 64, 384, sA);
    stageT<128, 8, 7, 0>(Bb + it * 64, 384, sB);
    __syncthreads();
    short8 Af[4][2], Bf[4][2];
#pragma unroll
    for (int mi = 0; mi < 4; ++mi) {
      int row = wr * 64 + mi * 16 + id16;
#pragma unroll
      for (int kk = 0; kk < 2; ++kk) Af[mi][kk] = fragLd<7, 0>(sA, row, kk * 4 + g, 64);
    }
#pragma unroll
    for (int ni = 0; ni < 4; ++ni) {
      int col = wc * 64 + ni * 16 + id16;
#pragma unroll
      for (int kk = 0; kk < 2; ++kk) Bf[ni][kk] = fragLd<7, 0>(sB, col, kk * 4 + g, 64);
    }
#pragma unroll
    for (int kk = 0; kk < 2; ++kk)
#pragma unroll
      for (int mi = 0; mi < 4; ++mi)
#pragma unroll
        for (int ni = 0; ni < 4; ++ni)
          acc[mi][ni] = __builtin_amdgcn_mfma_f32_16x16x32_bf16(Af[mi][kk], Bf[ni][kk],
                                                                acc[mi][ni], 0, 0, 0);
    __syncthreads();
  }
  int l4 = (lane >> 4) * 4;
#pragma unroll
  for (int mi = 0; mi < 4; ++mi)
#pragma unroll
    for (int ni = 0; ni < 4; ++ni) {
      int i0 = m0 + wr * 64 + mi * 16 + l4;
      int n = n0 + wc * 64 + ni * 16 + id16;
      int r = n >> 5, d = n & 31;
      f32x4 a = acc[mi][ni];
#pragma unroll
      for (int reg = 0; reg < 4; ++reg)
        out[(((size_t)r * 384 + i0 + reg) * 12 + h) * 32 + d] = a[reg];
    }
}

extern "C" void kernel_launch(void* const* d_in, const int* in_sizes, int n_in,
                              void* d_out, int out_size, void* d_ws, size_t ws_size,
                              hipStream_t stream) {
  const float* x = (const float*)d_in[0];
  const float* Wq = (const float*)d_in[1];
  const float* Wk = (const float*)d_in[2];
  const float* Wv = (const float*)d_in[3];
  const float* Wq_s = (const float*)d_in[4];
  const float* Wk_s = (const float*)d_in[5];
  const int* res_mask = (const int*)d_in[6];
  const int* seq_mask = (const int*)d_in[7];
  float* ws = (float*)d_ws;
  char* wsb = (char*)d_ws;
  float* out = (float*)d_out;

  unsigned short* Pb  = (unsigned short*)(wsb + o_p * 4);
  float* swT          = ws + o_logits;
  unsigned short* Wtb = (unsigned short*)(wsb + o_attn * 4);
  float* QKf0         = ws + o_attn;
  unsigned short* Q3b = (unsigned short*)(wsb + ob_q3b);
  unsigned short* K3b = (unsigned short*)(wsb + ob_k3b);
  unsigned short* V3b = (unsigned short*)(wsb + ob_v3b);
  unsigned short* xb  = (unsigned short*)(wsb + ob_xb);
  unsigned short* attnb = Q3b;
  float* QKf1 = (float*)(wsb + ob_xb);

  hipLaunchKernelGGL(k_cvt_x, dim3(9216), dim3(256), 0, stream, x, xb);
  hipLaunchKernelGGL(k_qs, dim3(C_), dim3(E_), 0, stream, x, Wq_s, ws);
  hipLaunchKernelGGL(k_p, dim3(16, C_), dim3(E_), 0, stream, Wk_s, ws, Pb);
  hipLaunchKernelGGL(k_logits_sm, dim3(C_), dim3(256), 0, stream, xb, Pb, seq_mask, swT);
  hipLaunchKernelGGL(k_cvt_w, dim3(1152), dim3(384), 0, stream, Wq, Wk, Wv, Wtb);
  hipLaunchKernelGGL(k_proj_all, dim3(6912), dim3(256), 0, stream, xb, Wtb, swT,
                     Q3b, K3b, V3b);
  hipLaunchKernelGGL(k_qk_mma, dim3(216), dim3(256), 0, stream, Q3b, K3b, QKf0, QKf1);
  hipLaunchKernelGGL(k_softmax_j, dim3(C_, H_), dim3(C_), 0, stream, res_mask,
                     QKf0, QKf1, attnb);
  hipLaunchKernelGGL(k_out_mma, dim3(2304), dim3(256), 0, stream, attnb, V3b, out);
}

// Round 15
// 373.055 us; speedup vs baseline: 7.1687x; 1.0710x over previous
//
#include <hip/hip_runtime.h>
#include <math.h>
#include <stdint.h>

#define DEV_INLINE __device__ __forceinline__

constexpr int R_ = 256, C_ = 384, E_ = 384, H_ = 12, D_ = 32;
constexpr float NEGF = -3.402823466e38f;

typedef __attribute__((ext_vector_type(4))) float f32x4;
typedef __attribute__((ext_vector_type(8))) short short8;
typedef __attribute__((ext_vector_type(4))) unsigned short u16x4;

// ---------------- workspace layout ----------------
constexpr size_t o_qs     = 0;                                 // C*E f32 (qs)
constexpr size_t o_p      = o_qs + (size_t)C_ * E_;            // Pb bf16 overlay
constexpr size_t o_logits = o_p + (size_t)C_ * H_ * E_;        // swT f32 [12][256][384]
constexpr size_t o_sw     = o_logits + (size_t)C_ * H_ * R_;   // (free)
constexpr size_t o_attn   = o_sw + (size_t)C_ * H_ * R_;       // QKf0; Wtb overlays pre-qk
constexpr size_t o_q3     = o_attn + (size_t)H_ * C_ * C_;
constexpr size_t SZBIG  = 75497472;                  // bytes per big region
constexpr size_t ob_q3b = o_q3 * 4;                  // 24,182,784 (attnb overlays after qk)
constexpr size_t ob_k3b = ob_q3b + SZBIG;
constexpr size_t ob_v3b = ob_k3b + SZBIG;
constexpr size_t ob_xb  = ob_v3b + SZBIG;            // ends 326,172,672; QKf1/2/3 overlay after proj
constexpr size_t QKSZ   = 7077888;                   // H*C*C*4 bytes

// ---------------- helpers ----------------
DEV_INLINE unsigned short bf16h(float x) {
  unsigned int u = __builtin_bit_cast(unsigned int, x);
  unsigned int r = (u + 0x7FFFu + ((u >> 16) & 1u)) >> 16;
  return (unsigned short)r;
}
DEV_INLINE float waveRedMax(float v) {
#pragma unroll
  for (int o = 32; o > 0; o >>= 1) v = fmaxf(v, __shfl_down(v, o));
  return v;
}
DEV_INLINE float waveRedSum(float v) {
#pragma unroll
  for (int o = 32; o > 0; o >>= 1) v += __shfl_down(v, o);
  return v;
}

// ---------------- async global->LDS staging (linear LDS + swizzled source) ----------------
DEV_INLINE void gll16(const void* g, void* l) {
  __builtin_amdgcn_global_load_lds(
      reinterpret_cast<__attribute__((address_space(1))) void*>(
          reinterpret_cast<uintptr_t>(g)),
      reinterpret_cast<__attribute__((address_space(3))) void*>(
          reinterpret_cast<uintptr_t>(l)),
      16, 0, 0);
}

template <int ROWS, int UPR, int MASK, int SHIFT>
DEV_INLINE void stageT(const unsigned short* __restrict__ g, int lda,
                       unsigned short* l) {
  int t = threadIdx.x, w = t >> 6, lane = t & 63;
  constexpr int NI = (ROWS * UPR) / 64;
  constexpr int PW = NI / 4;
#pragma unroll
  for (int j = 0; j < PW; ++j) {
    int u0 = (w * PW + j) * 64;
    int u = u0 + lane;
    int row = u / UPR, qp = u % UPR;
    int q = qp ^ ((row >> SHIFT) & MASK);
    gll16(g + (size_t)row * lda + q * 8, l + (size_t)u0 * 8);
  }
}

template <int MASK, int SHIFT>
DEV_INLINE short8 fragLd(const unsigned short* base, int row, int q, int rowShorts) {
  int qp = q ^ ((row >> SHIFT) & MASK);
  return *(const short8*)(base + row * rowShorts + qp * 8);
}

// ================= stage 1 =================
__global__ void k_qs(const float* __restrict__ x, const float* __restrict__ Wq_s,
                     float* __restrict__ ws) {
  int c = blockIdx.x, t = threadIdx.x;
  __shared__ float xl[E_];
  xl[t] = x[(size_t)c * E_ + t];
  __syncthreads();
  float s = 0.f;
#pragma unroll 8
  for (int k = 0; k < E_; ++k) s += xl[k] * Wq_s[(size_t)k * E_ + t];
  ws[o_qs + (size_t)c * E_ + t] = s * 0.17677669529663687f;
}

__global__ void k_p(const float* __restrict__ Wk_s, const float* __restrict__ ws,
                    unsigned short* __restrict__ Pb) {
  int h = blockIdx.x, c = blockIdx.y, t = threadIdx.x;
  __shared__ float q[D_];
  float s = 0.f;
  if (h < 12) {
    if (t < D_) q[t] = ws[o_qs + (size_t)c * E_ + h * D_ + t];
    __syncthreads();
    const float* wrow = &Wk_s[(size_t)t * E_ + h * D_];
#pragma unroll
    for (int d = 0; d < D_; d += 4) {
      float4 w = *(const float4*)&wrow[d];
      s += w.x * q[d] + w.y * q[d + 1] + w.z * q[d + 2] + w.w * q[d + 3];
    }
  }
  Pb[((size_t)c * 16 + h) * 384 + t] = bf16h(s);
}

// ---------------- fused logits + softmax_r -> swT[h][r][c] ----------------
__global__ __launch_bounds__(256) void k_logits_sm(
    const unsigned short* __restrict__ xb, const unsigned short* __restrict__ Pb,
    const int* __restrict__ seq_mask, float* __restrict__ swT) {
  int c = blockIdx.x, t = threadIdx.x;
  __shared__ unsigned short sA[256 * 32];
  __shared__ unsigned short sB[16 * 32];
  __shared__ float lg[12 * 256];
  __shared__ float red[4];
  int w = t >> 6, lane = t & 63, id16 = lane & 15, g = lane >> 4;
  f32x4 acc[4];
#pragma unroll
  for (int mi = 0; mi < 4; ++mi) acc[mi] = (f32x4){0.f, 0.f, 0.f, 0.f};

  for (int k0 = 0; k0 < 384; k0 += 32) {
    stageT<256, 4, 3, 0>(xb + (size_t)c * 384 + k0, 384 * 384, sA);
    if (w == 0) {
      int row = lane >> 2, qp = lane & 3, q = qp ^ (row & 3);
      gll16(Pb + ((size_t)c * 16 + row) * 384 + k0 + q * 8, sB);
    }
    __syncthreads();
    short8 Bf = fragLd<3, 0>(sB, id16, g, 32);
#pragma unroll
    for (int mi = 0; mi < 4; ++mi) {
      short8 Af = fragLd<3, 0>(sA, w * 64 + mi * 16 + id16, g, 32);
      acc[mi] = __builtin_amdgcn_mfma_f32_16x16x32_bf16(Af, Bf, acc[mi], 0, 0, 0);
    }
    __syncthreads();
  }
  int l4 = (lane >> 4) * 4;
#pragma unroll
  for (int mi = 0; mi < 4; ++mi) {
    if (id16 < 12) {
      f32x4 a = acc[mi];
#pragma unroll
      for (int reg = 0; reg < 4; ++reg)
        lg[id16 * 256 + w * 64 + mi * 16 + l4 + reg] = a[reg];
    }
  }
  __syncthreads();
  int wid = t >> 6;
  const float scal = 0.17677669529663687f / sqrtf((float)C_);
  bool masked = (seq_mask[t] == 0);
  for (int h = 0; h < 12; ++h) {
    float v = masked ? NEGF : lg[h * 256 + t];
    float m = waveRedMax(v);
    if ((t & 63) == 0) red[wid] = m;
    __syncthreads();
    float mx = fmaxf(fmaxf(red[0], red[1]), fmaxf(red[2], red[3]));
    __syncthreads();
    float e = expf(v - mx);
    float s = waveRedSum(e);
    if ((t & 63) == 0) red[wid] = s;
    __syncthreads();
    float sum = red[0] + red[1] + red[2] + red[3];
    swT[((size_t)h * 256 + t) * 384 + c] = e / sum * scal;
    __syncthreads();
  }
}

// ---------------- conversions ----------------
__global__ void k_cvt_x(const float* __restrict__ x, unsigned short* __restrict__ xb) {
  size_t i = ((size_t)blockIdx.x * 256 + threadIdx.x) * 16;
  unsigned short h[16];
#pragma unroll
  for (int j = 0; j < 4; ++j) {
    float4 f = *(const float4*)&x[i + j * 4];
    h[j * 4 + 0] = bf16h(f.x);
    h[j * 4 + 1] = bf16h(f.y);
    h[j * 4 + 2] = bf16h(f.z);
    h[j * 4 + 3] = bf16h(f.w);
  }
  *(short8*)&xb[i] = *(const short8*)&h[0];
  *(short8*)&xb[i + 8] = *(const short8*)&h[8];
}

__global__ void k_cvt_w(const float* __restrict__ Wq, const float* __restrict__ Wk,
                        const float* __restrict__ Wv, unsigned short* __restrict__ Wtb) {
  int n = blockIdx.x, k = threadIdx.x;
  const float* W;
  int col;
  if (n < 384)      { W = Wq; col = n; }
  else if (n < 768) { W = Wk; col = n - 384; }
  else              { W = Wv; col = n - 768; }
  Wtb[(size_t)n * 384 + k] = bf16h(W[(size_t)k * 384 + col]);
}

// ---------------- k_proj_all (R14-verified) ----------------
__global__ __launch_bounds__(256, 4) void k_proj_all(
    const unsigned short* __restrict__ xb, const unsigned short* __restrict__ Wtb,
    const float* __restrict__ swT, unsigned short* __restrict__ Q3b,
    unsigned short* __restrict__ K3b, unsigned short* __restrict__ V3b) {
  __shared__ __align__(16) unsigned short smem[2 * 128 * 64];
  unsigned short* sA = smem;
  unsigned short* sB = smem + 128 * 64;
  int Dd = blockIdx.x;                       // 6912 blocks; /8 = 864 -> bijective
  int L = (Dd & 7) * 864 + (Dd >> 3);
  int bm = L / 9, bn = L - bm * 9;
  int n0 = bn * 128, m0 = bm * 128;
  int wave = threadIdx.x >> 6, wr = wave >> 1, wc = wave & 1;
  int lane = threadIdx.x & 63, id16 = lane & 15, g = lane >> 4;
  f32x4 acc[4][4];
#pragma unroll
  for (int mi = 0; mi < 4; ++mi)
#pragma unroll
    for (int ni = 0; ni < 4; ++ni) acc[mi][ni] = (f32x4){0.f, 0.f, 0.f, 0.f};

  for (int it = 0; it < 6; ++it) {
    stageT<128, 8, 7, 0>(xb + (size_t)m0 * 384 + it * 64, 384, sA);
    stageT<128, 8, 7, 0>(Wtb + (size_t)n0 * 384 + it * 64, 384, sB);
    __syncthreads();
    short8 Af[4][2], Bf[4][2];
#pragma unroll
    for (int mi = 0; mi < 4; ++mi) {
      int row = wr * 64 + mi * 16 + id16;
#pragma unroll
      for (int kk = 0; kk < 2; ++kk) Af[mi][kk] = fragLd<7, 0>(sA, row, kk * 4 + g, 64);
    }
#pragma unroll
    for (int ni = 0; ni < 4; ++ni) {
      int col = wc * 64 + ni * 16 + id16;
#pragma unroll
      for (int kk = 0; kk < 2; ++kk) Bf[ni][kk] = fragLd<7, 0>(sB, col, kk * 4 + g, 64);
    }
#pragma unroll
    for (int kk = 0; kk < 2; ++kk)
#pragma unroll
      for (int mi = 0; mi < 4; ++mi)
#pragma unroll
        for (int ni = 0; ni < 4; ++ni)
          acc[mi][ni] = __builtin_amdgcn_mfma_f32_16x16x32_bf16(Af[mi][kk], Bf[ni][kk],
                                                                acc[mi][ni], 0, 0, 0);
    __syncthreads();
  }

  int l4 = (lane >> 4) * 4;
  int r = bm / 3, cb = (bm % 3) * 128;
  if (bn < 6) {
    bool isQ = bn < 3;
    int hbase = isQ ? bn * 4 : (bn - 3) * 4;
#pragma unroll
    for (int mi = 0; mi < 4; ++mi) {
      int clBase = wr * 64 + mi * 16 + l4;
#pragma unroll
      for (int ni = 0; ni < 4; ++ni) {
        int nl = wc * 64 + ni * 16 + id16;
        int hhl = nl >> 5, d = nl & 31;
        f32x4 a = acc[mi][ni];
        if (isQ) {
          float4 sv =
              *(const float4*)&swT[((size_t)(hbase + hhl) * 256 + r) * 384 + cb + clBase];
          a[0] *= sv.x; a[1] *= sv.y; a[2] *= sv.z; a[3] *= sv.w;
        }
#pragma unroll
        for (int reg = 0; reg < 4; ++reg)
          smem[hhl * 4096 + (clBase + reg) * 32 + d] = bf16h(a[reg]);
      }
    }
    __syncthreads();
    unsigned short* dst = isQ ? Q3b : K3b;
#pragma unroll
    for (int seg = 0; seg < 8; ++seg) {
      int off = seg * 2048 + threadIdx.x * 8;
      int hhl = off >> 12, inner = off & 4095;
      int hg = hbase + hhl;
      *(short8*)(dst + (((size_t)hg * 256 + r) * 384 + cb) * 32 + inner) =
          *(const short8*)(smem + off);
    }
  } else {  // V: V3b[h][r*32+d][c]
#pragma unroll
    for (int mi = 0; mi < 4; ++mi) {
      int c0 = cb + wr * 64 + mi * 16 + l4;
#pragma unroll
      for (int ni = 0; ni < 4; ++ni) {
        int nv = n0 + wc * 64 + ni * 16 + id16 - 768;
        int hh = nv >> 5, dd = nv & 31;
        f32x4 a = acc[mi][ni];
        u16x4 hv;
#pragma unroll
        for (int reg = 0; reg < 4; ++reg) hv[reg] = bf16h(a[reg]);
        *(u16x4*)(V3b + ((size_t)hh * 8192 + r * 32 + dd) * 384 + c0) = hv;
      }
    }
  }
}

// ---------------- k_qk_mma: 128x128 tiles, split-K x4 -> 432 blocks ----------------
__global__ __launch_bounds__(256, 4) void k_qk_mma(
    const unsigned short* __restrict__ Q3b, const unsigned short* __restrict__ K3b,
    float* __restrict__ QKf0, float* __restrict__ QKf1,
    float* __restrict__ QKf2, float* __restrict__ QKf3) {
  __shared__ unsigned short sA[2 * 4096], sB[2 * 4096];  // 16KB each
  int Dd = blockIdx.x;                       // 432 blocks; /8 = 54 -> bijective
  int L = (Dd & 7) * 54 + (Dd >> 3);
  int kh = L / 108, rem = L - kh * 108;
  int h = rem / 9, r2 = rem - h * 9, bi = r2 / 3, bj = r2 - bi * 3;
  int i0 = bi * 128, j0 = bj * 128;
  int wave = threadIdx.x >> 6, wr = wave >> 1, wc = wave & 1;
  int lane = threadIdx.x & 63, id16 = lane & 15, g = lane >> 4;
  f32x4 acc[4][4];
#pragma unroll
  for (int mi = 0; mi < 4; ++mi)
#pragma unroll
    for (int ni = 0; ni < 4; ++ni) acc[mi][ni] = (f32x4){0.f, 0.f, 0.f, 0.f};

  for (int it = 0; it < 32; ++it) {
    int r = kh * 64 + it * 2;
#pragma unroll
    for (int rr = 0; rr < 2; ++rr) {
      stageT<128, 4, 3, 1>(Q3b + (((size_t)h * 256 + r + rr) * 384 + i0) * 32, 32,
                           sA + rr * 4096);
      stageT<128, 4, 3, 1>(K3b + (((size_t)h * 256 + r + rr) * 384 + j0) * 32, 32,
                           sB + rr * 4096);
    }
    __syncthreads();
#pragma unroll
    for (int rr = 0; rr < 2; ++rr) {
      short8 Af[4], Bf[4];
#pragma unroll
      for (int mi = 0; mi < 4; ++mi)
        Af[mi] = fragLd<3, 1>(sA + rr * 4096, wr * 64 + mi * 16 + id16, g, 32);
#pragma unroll
      for (int ni = 0; ni < 4; ++ni)
        Bf[ni] = fragLd<3, 1>(sB + rr * 4096, wc * 64 + ni * 16 + id16, g, 32);
#pragma unroll
      for (int mi = 0; mi < 4; ++mi)
#pragma unroll
        for (int ni = 0; ni < 4; ++ni)
          acc[mi][ni] = __builtin_amdgcn_mfma_f32_16x16x32_bf16(Af[mi], Bf[ni],
                                                                acc[mi][ni], 0, 0, 0);
    }
    __syncthreads();
  }
  int l4 = (lane >> 4) * 4;
  float* dst = (kh == 0) ? QKf0 : (kh == 1) ? QKf1 : (kh == 2) ? QKf2 : QKf3;
#pragma unroll
  for (int mi = 0; mi < 4; ++mi)
#pragma unroll
    for (int ni = 0; ni < 4; ++ni) {
      int ii = i0 + wr * 64 + mi * 16 + l4;
      int j = j0 + wc * 64 + ni * 16 + id16;
      f32x4 a = acc[mi][ni];
#pragma unroll
      for (int reg = 0; reg < 4; ++reg)
        dst[((size_t)h * 384 + ii + reg) * 384 + j] = a[reg];
    }
}

// ---------------- k_softmax_j: sum 4 split-K partials, softmax, emit bf16 ----------------
__global__ void k_softmax_j(const int* __restrict__ res_mask, const float* __restrict__ QKf0,
                            const float* __restrict__ QKf1, const float* __restrict__ QKf2,
                            const float* __restrict__ QKf3,
                            unsigned short* __restrict__ attnb) {
  int i = blockIdx.x, h = blockIdx.y, t = threadIdx.x;
  int lane = t & 63, wid = t >> 6;
  size_t base = ((size_t)h * C_ + i) * C_;
  float v = (QKf0[base + t] + QKf1[base + t]) + (QKf2[base + t] + QKf3[base + t]);
  if ((res_mask[i] * res_mask[t]) == 0) v = NEGF;
  __shared__ float red[6];
  float m = waveRedMax(v);
  if (lane == 0) red[wid] = m;
  __syncthreads();
  float mx = red[0];
#pragma unroll
  for (int w = 1; w < 6; ++w) mx = fmaxf(mx, red[w]);
  __syncthreads();
  float e = expf(v - mx);
  float s = waveRedSum(e);
  if (lane == 0) red[wid] = s;
  __syncthreads();
  float sum = 0.f;
#pragma unroll
  for (int w = 0; w < 6; ++w) sum += red[w];
  attnb[base + t] = bf16h(e / sum);
}

// ---------------- k_out_mma: 128x128 tile, BK=64, LDS-transpose f32 epilogue ----------------
__global__ __launch_bounds__(256, 4) void k_out_mma(
    const unsigned short* __restrict__ attnb, const unsigned short* __restrict__ V3b,
    float* __restrict__ out) {
  __shared__ __align__(16) unsigned short smem[2 * 128 * 64];  // 32KB; reused as f32 epi
  unsigned short* sA = smem;
  unsigned short* sB = smem + 128 * 64;
  int Dd = blockIdx.x;                        // 2304 blocks; /8 = 288 -> bijective
  int L = (Dd & 7) * 288 + (Dd >> 3);
  int bn = L % 64, bm = (L / 64) % 3, h = L / 192;
  int n0 = bn * 128, m0 = bm * 128;
  int wave = threadIdx.x >> 6, wr = wave >> 1, wc = wave & 1;
  int lane = threadIdx.x & 63, id16 = lane & 15, g = lane >> 4;
  f32x4 acc[4][4];
#pragma unroll
  for (int mi = 0; mi < 4; ++mi)
#pragma unroll
    for (int ni = 0; ni < 4; ++ni) acc[mi][ni] = (f32x4){0.f, 0.f, 0.f, 0.f};
  const unsigned short* Ab = attnb + (size_t)h * 384 * 384 + (size_t)m0 * 384;
  const unsigned short* Bb = V3b + (size_t)h * 8192 * 384 + (size_t)n0 * 384;

  for (int it = 0; it < 6; ++it) {
    stageT<128, 8, 7, 0>(Ab + it * 64, 384, sA);
    stageT<128, 8, 7, 0>(Bb + it * 64, 384, sB);
    __syncthreads();
    short8 Af[4][2], Bf[4][2];
#pragma unroll
    for (int mi = 0; mi < 4; ++mi) {
      int row = wr * 64 + mi * 16 + id16;
#pragma unroll
      for (int kk = 0; kk < 2; ++kk) Af[mi][kk] = fragLd<7, 0>(sA, row, kk * 4 + g, 64);
    }
#pragma unroll
    for (int ni = 0; ni < 4; ++ni) {
      int col = wc * 64 + ni * 16 + id16;
#pragma unroll
      for (int kk = 0; kk < 2; ++kk) Bf[ni][kk] = fragLd<7, 0>(sB, col, kk * 4 + g, 64);
    }
#pragma unroll
    for (int kk = 0; kk < 2; ++kk)
#pragma unroll
      for (int mi = 0; mi < 4; ++mi)
#pragma unroll
        for (int ni = 0; ni < 4; ++ni)
          acc[mi][ni] = __builtin_amdgcn_mfma_f32_16x16x32_bf16(Af[mi][kk], Bf[ni][kk],
                                                                acc[mi][ni], 0, 0, 0);
    __syncthreads();
  }

  // Epilogue: two passes; stage [plane(wc) 2][i 128][d 32] f32 in LDS, write float4.
  int l4 = (lane >> 4) * 4;
  float* smf = (float*)smem;
#pragma unroll
  for (int p = 0; p < 2; ++p) {
#pragma unroll
    for (int mi = 0; mi < 4; ++mi) {
      int iL = wr * 64 + mi * 16 + l4;
#pragma unroll
      for (int nq = 0; nq < 2; ++nq) {
        int ni = 2 * p + nq;
        int d = nq * 16 + id16;
        f32x4 a = acc[mi][ni];
#pragma unroll
        for (int reg = 0; reg < 4; ++reg)
          smf[wc * 4096 + (iL + reg) * 32 + d] = a[reg];
      }
    }
    __syncthreads();
#pragma unroll
    for (int seg = 0; seg < 8; ++seg) {
      int o = seg * 1024 + threadIdx.x * 4;
      int plane = o >> 12, rest = o & 4095;
      int iL = rest >> 5, d = rest & 31;
      int rg = (n0 >> 5) + plane * 2 + p;
      *(float4*)&out[(((size_t)rg * 384 + m0 + iL) * 12 + h) * 32 + d] =
          *(const float4*)&smf[o];
    }
    __syncthreads();
  }
}

extern "C" void kernel_launch(void* const* d_in, const int* in_sizes, int n_in,
                              void* d_out, int out_size, void* d_ws, size_t ws_size,
                              hipStream_t stream) {
  const float* x = (const float*)d_in[0];
  const float* Wq = (const float*)d_in[1];
  const float* Wk = (const float*)d_in[2];
  const float* Wv = (const float*)d_in[3];
  const float* Wq_s = (const float*)d_in[4];
  const float* Wk_s = (const float*)d_in[5];
  const int* res_mask = (const int*)d_in[6];
  const int* seq_mask = (const int*)d_in[7];
  float* ws = (float*)d_ws;
  char* wsb = (char*)d_ws;
  float* out = (float*)d_out;

  unsigned short* Pb  = (unsigned short*)(wsb + o_p * 4);
  float* swT          = ws + o_logits;
  unsigned short* Wtb = (unsigned short*)(wsb + o_attn * 4);
  float* QKf0         = ws + o_attn;
  unsigned short* Q3b = (unsigned short*)(wsb + ob_q3b);
  unsigned short* K3b = (unsigned short*)(wsb + ob_k3b);
  unsigned short* V3b = (unsigned short*)(wsb + ob_v3b);
  unsigned short* xb  = (unsigned short*)(wsb + ob_xb);
  unsigned short* attnb = Q3b;
  float* QKf1 = (float*)(wsb + ob_xb);
  float* QKf2 = (float*)(wsb + ob_xb + QKSZ);
  float* QKf3 = (float*)(wsb + ob_xb + 2 * QKSZ);

  hipLaunchKernelGGL(k_cvt_x, dim3(9216), dim3(256), 0, stream, x, xb);
  hipLaunchKernelGGL(k_qs, dim3(C_), dim3(E_), 0, stream, x, Wq_s, ws);
  hipLaunchKernelGGL(k_p, dim3(16, C_), dim3(E_), 0, stream, Wk_s, ws, Pb);
  hipLaunchKernelGGL(k_logits_sm, dim3(C_), dim3(256), 0, stream, xb, Pb, seq_mask, swT);
  hipLaunchKernelGGL(k_cvt_w, dim3(1152), dim3(384), 0, stream, Wq, Wk, Wv, Wtb);
  hipLaunchKernelGGL(k_proj_all, dim3(6912), dim3(256), 0, stream, xb, Wtb, swT,
                     Q3b, K3b, V3b);
  hipLaunchKernelGGL(k_qk_mma, dim3(432), dim3(256), 0, stream, Q3b, K3b,
                     QKf0, QKf1, QKf2, QKf3);
  hipLaunchKernelGGL(k_softmax_j, dim3(C_, H_), dim3(C_), 0, stream, res_mask,
                     QKf0, QKf1, QKf2, QKf3, attnb);
  hipLaunchKernelGGL(k_out_mma, dim3(2304), dim3(256), 0, stream, attnb, V3b, out);
}